// Round 1
// baseline (2172.327 us; speedup 1.0000x reference)
//
#include <hip/hip_runtime.h>
#include <math.h>

// nGPT attention, fp32 baseline.
// B=2, T=2048, C=1024, H=16, D=64.
// Precision note: logits ~N(0,1024) -> softmax is near-one-hot; bf16 MFMA on the
// Q/K path would flip argmaxes (delta~30 on logits). Keep Q/K path fp32.
// RoPE angles in double (t*invf up to 2047 rad).

#define BM 128
#define BN 128
#define BKK 8

// C[m][n] = sum_k A[m*K+k] * B[n*K+k]   (i.e. A @ B^T, both row-major, K contig)
__device__ __forceinline__ void sgemm_body(const float* __restrict__ A,
                                           const float* __restrict__ Bm,
                                           float* __restrict__ Cm,
                                           int K, int N, int bm, int bn)
{
    __shared__ float As[BKK][BM + 4];
    __shared__ float Bs[BKK][BN + 4];
    const int tid = threadIdx.x;
    const int lr = tid >> 1;            // 0..127 : row within tile for loading
    const int lk = (tid & 1) << 2;      // 0 or 4 : k-offset for loading
    const float* Ald = A + (size_t)(bm + lr) * K + lk;
    const float* Bld = Bm + (size_t)(bn + lr) * K + lk;
    const int tr = (tid & 15) << 3;     // 0..120 : output row block
    const int tc = (tid >> 4) << 3;     // 0..120 : output col block

    float acc[8][8];
#pragma unroll
    for (int i = 0; i < 8; ++i)
#pragma unroll
        for (int j = 0; j < 8; ++j) acc[i][j] = 0.f;

    for (int kt = 0; kt < K; kt += BKK) {
        float4 av = *(const float4*)(Ald + kt);
        float4 bv = *(const float4*)(Bld + kt);
        __syncthreads();
        As[lk + 0][lr] = av.x; As[lk + 1][lr] = av.y;
        As[lk + 2][lr] = av.z; As[lk + 3][lr] = av.w;
        Bs[lk + 0][lr] = bv.x; Bs[lk + 1][lr] = bv.y;
        Bs[lk + 2][lr] = bv.z; Bs[lk + 3][lr] = bv.w;
        __syncthreads();
#pragma unroll
        for (int kk = 0; kk < BKK; ++kk) {
            float a[8], b[8];
#pragma unroll
            for (int i = 0; i < 8; ++i) a[i] = As[kk][tr + i];
#pragma unroll
            for (int j = 0; j < 8; ++j) b[j] = Bs[kk][tc + j];
#pragma unroll
            for (int i = 0; i < 8; ++i)
#pragma unroll
                for (int j = 0; j < 8; ++j)
                    acc[i][j] += a[i] * b[j];
        }
    }

#pragma unroll
    for (int i = 0; i < 8; ++i) {
        float* crow = Cm + (size_t)(bm + tr + i) * N + (bn + tc);
        float4 v0 = make_float4(acc[i][0], acc[i][1], acc[i][2], acc[i][3]);
        float4 v1 = make_float4(acc[i][4], acc[i][5], acc[i][6], acc[i][7]);
        *(float4*)(crow) = v0;
        *(float4*)(crow + 4) = v1;
    }
}

__global__ __launch_bounds__(256) void sgemm_qkv(const float* __restrict__ x,
    const float* __restrict__ Wq, const float* __restrict__ Wk,
    const float* __restrict__ Wv,
    float* __restrict__ Qo, float* __restrict__ Ko, float* __restrict__ Vo,
    int N, int K)
{
    const float* W;
    float* O;
    if (blockIdx.z == 0)      { W = Wq; O = Qo; }
    else if (blockIdx.z == 1) { W = Wk; O = Ko; }
    else                      { W = Wv; O = Vo; }
    sgemm_body(x, W, O, K, N, blockIdx.x * BM, blockIdx.y * BN);
}

__global__ __launch_bounds__(256) void sgemm_one(const float* __restrict__ A,
    const float* __restrict__ W, float* __restrict__ O, int N, int K)
{
    sgemm_body(A, W, O, K, N, blockIdx.x * BM, blockIdx.y * BN);
}

// One wave per (b,t,h,{q|k}); lane = d. In-place RoPE + L2-normalize + scale.
// Q additionally gets the attention sqrt(D)=8 folded in.
__global__ __launch_bounds__(256) void rope_norm(float* __restrict__ Q,
                                                 float* __restrict__ K,
                                                 const float* __restrict__ s_qk)
{
    constexpr int T = 2048, H = 16, D = 64;
    int wid = blockIdx.x * 4 + (threadIdx.x >> 6);
    const int lane = threadIdx.x & 63;
    const int sel = wid & 1; wid >>= 1;       // 0 = Q, 1 = K
    const int h = wid & (H - 1); wid >>= 4;
    const int t = wid & (T - 1); wid >>= 11;
    const int b = wid;                        // 0..1

    float* ptr = (sel ? K : Q) + (((size_t)(b * T + t)) * H + h) * D;
    float v = ptr[lane];

    const int p = lane >> 1;
    double invf = pow(10000.0, -(double)p / 32.0);   // theta^{-2p/D}, D=64
    double sd, cd;
    sincos((double)t * invf, &sd, &cd);
    const float sn = (float)sd, cs = (float)cd;

    float partner = __shfl_xor(v, 1, 64);
    float rot = (lane & 1) ? partner : -partner;     // rotate_half interleaved
    float r = v * cs + rot * sn;

    float ssq = r * r;
#pragma unroll
    for (int off = 32; off; off >>= 1) ssq += __shfl_xor(ssq, off, 64);
    float nrm = fmaxf(sqrtf(ssq), 1e-12f);

    // scale = s_qk * s_qk_init / s_qk_scale = s_qk * sqrt(C) = s_qk * 32
    float scale = s_qk[h * D + lane] * 32.0f;
    if (!sel) scale *= 8.0f;                         // fold sqrt(D) into Q
    ptr[lane] = r / nrm * scale;
}

// Flash attention, fp32. Each thread owns one full q row (registers); K/V tiles
// in LDS read as wave-broadcasts (all lanes same address -> conflict-free).
#define ABK 32
__global__ __launch_bounds__(256) void attn(const float* __restrict__ Q,
                                            const float* __restrict__ Kt,
                                            const float* __restrict__ V,
                                            float* __restrict__ Y)
{
    constexpr int T = 2048, H = 16, D = 64, C = H * D;
    __shared__ float Ks[ABK][D];
    __shared__ float Vs[ABK][D];

    const int bh = blockIdx.y;
    const int h = bh & (H - 1);
    const int b = bh >> 4;
    const int q = blockIdx.x * 256 + threadIdx.x;

    const float* qptr = Q + ((size_t)(b * T + q) * C + h * D);
    float qv[64];
#pragma unroll
    for (int i = 0; i < 64; i += 4) {
        float4 t4 = *(const float4*)(qptr + i);
        qv[i] = t4.x; qv[i + 1] = t4.y; qv[i + 2] = t4.z; qv[i + 3] = t4.w;
    }

    float o[64];
#pragma unroll
    for (int i = 0; i < 64; ++i) o[i] = 0.f;
    float mval = -1e30f, l = 0.f;

    const float* kbase = Kt + (size_t)(b * T) * C + h * D;
    const float* vbase = V + (size_t)(b * T) * C + h * D;

    for (int kt = 0; kt < T; kt += ABK) {
        __syncthreads();
        {
            const int row = threadIdx.x >> 4;          // 0..15
            const int col = (threadIdx.x & 15) << 2;   // 0..60
#pragma unroll
            for (int r = 0; r < ABK; r += 16) {
                *(float4*)&Ks[row + r][col] =
                    *(const float4*)(kbase + (size_t)(kt + row + r) * C + col);
                *(float4*)&Vs[row + r][col] =
                    *(const float4*)(vbase + (size_t)(kt + row + r) * C + col);
            }
        }
        __syncthreads();

        float sv[ABK];
#pragma unroll 4
        for (int j = 0; j < ABK; ++j) {
            float s0 = 0.f, s1 = 0.f, s2 = 0.f, s3 = 0.f;
#pragma unroll
            for (int c = 0; c < 64; c += 4) {
                float4 k4 = *(const float4*)&Ks[j][c];
                s0 += qv[c + 0] * k4.x;
                s1 += qv[c + 1] * k4.y;
                s2 += qv[c + 2] * k4.z;
                s3 += qv[c + 3] * k4.w;
            }
            sv[j] = (s0 + s1) + (s2 + s3);
        }

        float mt = mval;
#pragma unroll
        for (int j = 0; j < ABK; ++j) mt = fmaxf(mt, sv[j]);
        float fac = expf(mval - mt);
        mval = mt;
        l *= fac;
#pragma unroll
        for (int c = 0; c < 64; ++c) o[c] *= fac;
#pragma unroll
        for (int j = 0; j < ABK; ++j) {
            sv[j] = expf(sv[j] - mt);
            l += sv[j];
        }
#pragma unroll 4
        for (int j = 0; j < ABK; ++j) {
            const float p = sv[j];
#pragma unroll
            for (int c = 0; c < 64; c += 4) {
                float4 v4 = *(const float4*)&Vs[j][c];
                o[c + 0] += p * v4.x;
                o[c + 1] += p * v4.y;
                o[c + 2] += p * v4.z;
                o[c + 3] += p * v4.w;
            }
        }
    }

    const float inv = 1.0f / l;
    float* yp = Y + ((size_t)(b * T + q) * C + h * D);
#pragma unroll
    for (int c = 0; c < 64; c += 4) {
        float4 w4 = make_float4(o[c] * inv, o[c + 1] * inv,
                                o[c + 2] * inv, o[c + 3] * inv);
        *(float4*)(yp + c) = w4;
    }
}

extern "C" void kernel_launch(void* const* d_in, const int* in_sizes, int n_in,
                              void* d_out, int out_size, void* d_ws, size_t ws_size,
                              hipStream_t stream)
{
    const float* x    = (const float*)d_in[0];
    const float* Wq   = (const float*)d_in[1];
    const float* Wk   = (const float*)d_in[2];
    const float* Wv   = (const float*)d_in[3];
    const float* Wo   = (const float*)d_in[4];
    const float* s_qk = (const float*)d_in[5];
    float* out = (float*)d_out;

    constexpr int B = 2, T = 2048, C = 1024, H = 16;
    constexpr int M = B * T;                 // 4096
    const size_t mat = (size_t)M * C;        // 4M floats = 16 MB

    float* Qb = (float*)d_ws;
    float* Kb = Qb + mat;
    float* Vb = Kb + mat;
    float* Yb = Vb + mat;

    dim3 blk(256);

    // 1) Q,K,V = x @ W^T  (fused in one launch, 768 blocks = 3/CU)
    dim3 gqkv(M / BM, C / BN, 3);
    sgemm_qkv<<<gqkv, blk, 0, stream>>>(x, Wq, Wk, Wv, Qb, Kb, Vb, C, C);

    // 2) RoPE + normalize + scale (in place on Q,K)
    rope_norm<<<dim3(2 * B * T * H / 4), blk, 0, stream>>>(Qb, Kb, s_qk);

    // 3) attention -> Y in [B,T,H,D] layout
    attn<<<dim3(T / 256, B * H), blk, 0, stream>>>(Qb, Kb, Vb, Yb);

    // 4) out = Y @ Wo^T
    dim3 go(M / BM, C / BN);
    sgemm_one<<<go, blk, 0, stream>>>(Yb, Wo, out, C, C);
}

// Round 2
// 1749.434 us; speedup vs baseline: 1.2417x; 1.2417x over previous
//
#include <hip/hip_runtime.h>
#include <math.h>

// nGPT attention. B=2, T=2048, C=1024, H=16, D=64.
// Precision: logits ~N(0,1024) -> softmax near-one-hot; Q/K path must be fp32
// (bf16 noise ~3 on logits flips near-tied rows -> O(1) output errors).
// RoPE angles in double (t*invf up to 2047 rad).
// R2: attn restructured to 4 lanes per q-row (G=4) for 4x wave count
//     (1 -> 4 waves/SIMD); was occupancy-bound at 12%.

#define BM 128
#define BN 128
#define BKK 8

// C[m][n] = sum_k A[m*K+k] * B[n*K+k]   (i.e. A @ B^T, both row-major, K contig)
__device__ __forceinline__ void sgemm_body(const float* __restrict__ A,
                                           const float* __restrict__ Bm,
                                           float* __restrict__ Cm,
                                           int K, int N, int bm, int bn)
{
    __shared__ float As[BKK][BM + 4];
    __shared__ float Bs[BKK][BN + 4];
    const int tid = threadIdx.x;
    const int lr = tid >> 1;            // 0..127 : row within tile for loading
    const int lk = (tid & 1) << 2;      // 0 or 4 : k-offset for loading
    const float* Ald = A + (size_t)(bm + lr) * K + lk;
    const float* Bld = Bm + (size_t)(bn + lr) * K + lk;
    const int tr = (tid & 15) << 3;     // 0..120 : output row block
    const int tc = (tid >> 4) << 3;     // 0..120 : output col block

    float acc[8][8];
#pragma unroll
    for (int i = 0; i < 8; ++i)
#pragma unroll
        for (int j = 0; j < 8; ++j) acc[i][j] = 0.f;

    for (int kt = 0; kt < K; kt += BKK) {
        float4 av = *(const float4*)(Ald + kt);
        float4 bv = *(const float4*)(Bld + kt);
        __syncthreads();
        As[lk + 0][lr] = av.x; As[lk + 1][lr] = av.y;
        As[lk + 2][lr] = av.z; As[lk + 3][lr] = av.w;
        Bs[lk + 0][lr] = bv.x; Bs[lk + 1][lr] = bv.y;
        Bs[lk + 2][lr] = bv.z; Bs[lk + 3][lr] = bv.w;
        __syncthreads();
#pragma unroll
        for (int kk = 0; kk < BKK; ++kk) {
            float a[8], b[8];
#pragma unroll
            for (int i = 0; i < 8; ++i) a[i] = As[kk][tr + i];
#pragma unroll
            for (int j = 0; j < 8; ++j) b[j] = Bs[kk][tc + j];
#pragma unroll
            for (int i = 0; i < 8; ++i)
#pragma unroll
                for (int j = 0; j < 8; ++j)
                    acc[i][j] += a[i] * b[j];
        }
    }

#pragma unroll
    for (int i = 0; i < 8; ++i) {
        float* crow = Cm + (size_t)(bm + tr + i) * N + (bn + tc);
        float4 v0 = make_float4(acc[i][0], acc[i][1], acc[i][2], acc[i][3]);
        float4 v1 = make_float4(acc[i][4], acc[i][5], acc[i][6], acc[i][7]);
        *(float4*)(crow) = v0;
        *(float4*)(crow + 4) = v1;
    }
}

__global__ __launch_bounds__(256) void sgemm_qkv(const float* __restrict__ x,
    const float* __restrict__ Wq, const float* __restrict__ Wk,
    const float* __restrict__ Wv,
    float* __restrict__ Qo, float* __restrict__ Ko, float* __restrict__ Vo,
    int N, int K)
{
    const float* W;
    float* O;
    if (blockIdx.z == 0)      { W = Wq; O = Qo; }
    else if (blockIdx.z == 1) { W = Wk; O = Ko; }
    else                      { W = Wv; O = Vo; }
    sgemm_body(x, W, O, K, N, blockIdx.x * BM, blockIdx.y * BN);
}

__global__ __launch_bounds__(256) void sgemm_one(const float* __restrict__ A,
    const float* __restrict__ W, float* __restrict__ O, int N, int K)
{
    sgemm_body(A, W, O, K, N, blockIdx.x * BM, blockIdx.y * BN);
}

// One wave per (b,t,h,{q|k}); lane = d. In-place RoPE + L2-normalize + scale.
// Q additionally gets the attention sqrt(D)=8 folded in.
__global__ __launch_bounds__(256) void rope_norm(float* __restrict__ Q,
                                                 float* __restrict__ K,
                                                 const float* __restrict__ s_qk)
{
    constexpr int T = 2048, H = 16, D = 64;
    int wid = blockIdx.x * 4 + (threadIdx.x >> 6);
    const int lane = threadIdx.x & 63;
    const int sel = wid & 1; wid >>= 1;       // 0 = Q, 1 = K
    const int h = wid & (H - 1); wid >>= 4;
    const int t = wid & (T - 1); wid >>= 11;
    const int b = wid;                        // 0..1

    float* ptr = (sel ? K : Q) + (((size_t)(b * T + t)) * H + h) * D;
    float v = ptr[lane];

    const int p = lane >> 1;
    double invf = pow(10000.0, -(double)p / 32.0);   // theta^{-2p/D}, D=64
    double sd, cd;
    sincos((double)t * invf, &sd, &cd);
    const float sn = (float)sd, cs = (float)cd;

    float partner = __shfl_xor(v, 1, 64);
    float rot = (lane & 1) ? partner : -partner;     // rotate_half interleaved
    float r = v * cs + rot * sn;

    float ssq = r * r;
#pragma unroll
    for (int off = 32; off; off >>= 1) ssq += __shfl_xor(ssq, off, 64);
    float nrm = fmaxf(sqrtf(ssq), 1e-12f);

    // scale = s_qk * s_qk_init / s_qk_scale = s_qk * sqrt(C) = s_qk * 32
    float scale = s_qk[h * D + lane] * 32.0f;
    if (!sel) scale *= 8.0f;                         // fold sqrt(D) into Q
    ptr[lane] = r / nrm * scale;
}

// Flash attention, fp32. G=4 lanes per q-row; each lane owns 16 of the 64 dims
// of q and o. QK dot reduced across the 4 lanes with shfl_xor(1,2); softmax
// state (m,l) computed redundantly per lane. 64 q-rows per 256-thread block ->
// grid 1024 blocks = 4 blocks/CU = 16 waves/CU (4/SIMD).
#define ABK 32
#define DCH 16   // dims per lane = D / G
__global__ __launch_bounds__(256) void attn(const float* __restrict__ Q,
                                            const float* __restrict__ Kt,
                                            const float* __restrict__ V,
                                            float* __restrict__ Y)
{
    constexpr int T = 2048, H = 16, D = 64, C = H * D;
    __shared__ float Ks[ABK][D];
    __shared__ float Vs[ABK][D];

    const int bh = blockIdx.y;
    const int h = bh & (H - 1);
    const int b = bh >> 4;
    const int r = threadIdx.x >> 2;               // 0..63 : q-row within block
    const int c16 = (threadIdx.x & 3) * DCH;      // 0,16,32,48 : dim chunk
    const int q = blockIdx.x * 64 + r;

    const float* qptr = Q + ((size_t)(b * T + q) * C + h * D) + c16;
    float qv[DCH];
#pragma unroll
    for (int i = 0; i < DCH; i += 4) {
        float4 t4 = *(const float4*)(qptr + i);
        qv[i] = t4.x; qv[i + 1] = t4.y; qv[i + 2] = t4.z; qv[i + 3] = t4.w;
    }

    float o[DCH];
#pragma unroll
    for (int i = 0; i < DCH; ++i) o[i] = 0.f;
    float mval = -1e30f, l = 0.f;

    const float* kbase = Kt + (size_t)(b * T) * C + h * D;
    const float* vbase = V + (size_t)(b * T) * C + h * D;

    for (int kt = 0; kt < T; kt += ABK) {
        __syncthreads();
        {
            const int row = threadIdx.x >> 4;          // 0..15
            const int col = (threadIdx.x & 15) << 2;   // 0..60
#pragma unroll
            for (int rr = 0; rr < ABK; rr += 16) {
                *(float4*)&Ks[row + rr][col] =
                    *(const float4*)(kbase + (size_t)(kt + row + rr) * C + col);
                *(float4*)&Vs[row + rr][col] =
                    *(const float4*)(vbase + (size_t)(kt + row + rr) * C + col);
            }
        }
        __syncthreads();

        float sv[ABK];
#pragma unroll 4
        for (int j = 0; j < ABK; ++j) {
            float s0 = 0.f, s1 = 0.f, s2 = 0.f, s3 = 0.f;
#pragma unroll
            for (int i = 0; i < DCH; i += 4) {
                float4 k4 = *(const float4*)&Ks[j][c16 + i];
                s0 += qv[i + 0] * k4.x;
                s1 += qv[i + 1] * k4.y;
                s2 += qv[i + 2] * k4.z;
                s3 += qv[i + 3] * k4.w;
            }
            float s = (s0 + s1) + (s2 + s3);
            s += __shfl_xor(s, 1, 64);                 // reduce across the
            s += __shfl_xor(s, 2, 64);                 // 4 chunk-lanes
            sv[j] = s;
        }

        float mt = mval;
#pragma unroll
        for (int j = 0; j < ABK; ++j) mt = fmaxf(mt, sv[j]);
        float fac = expf(mval - mt);
        mval = mt;
        l *= fac;
#pragma unroll
        for (int i = 0; i < DCH; ++i) o[i] *= fac;
#pragma unroll
        for (int j = 0; j < ABK; ++j) {
            sv[j] = expf(sv[j] - mt);
            l += sv[j];
        }
#pragma unroll 4
        for (int j = 0; j < ABK; ++j) {
            const float p = sv[j];
#pragma unroll
            for (int i = 0; i < DCH; i += 4) {
                float4 v4 = *(const float4*)&Vs[j][c16 + i];
                o[i + 0] += p * v4.x;
                o[i + 1] += p * v4.y;
                o[i + 2] += p * v4.z;
                o[i + 3] += p * v4.w;
            }
        }
    }

    const float inv = 1.0f / l;
    float* yp = Y + ((size_t)(b * T + q) * C + h * D) + c16;
#pragma unroll
    for (int i = 0; i < DCH; i += 4) {
        float4 w4 = make_float4(o[i] * inv, o[i + 1] * inv,
                                o[i + 2] * inv, o[i + 3] * inv);
        *(float4*)(yp + i) = w4;
    }
}

extern "C" void kernel_launch(void* const* d_in, const int* in_sizes, int n_in,
                              void* d_out, int out_size, void* d_ws, size_t ws_size,
                              hipStream_t stream)
{
    const float* x    = (const float*)d_in[0];
    const float* Wq   = (const float*)d_in[1];
    const float* Wk   = (const float*)d_in[2];
    const float* Wv   = (const float*)d_in[3];
    const float* Wo   = (const float*)d_in[4];
    const float* s_qk = (const float*)d_in[5];
    float* out = (float*)d_out;

    constexpr int B = 2, T = 2048, C = 1024, H = 16;
    constexpr int M = B * T;                 // 4096
    const size_t mat = (size_t)M * C;        // 4M floats = 16 MB

    float* Qb = (float*)d_ws;
    float* Kb = Qb + mat;
    float* Vb = Kb + mat;
    float* Yb = Vb + mat;

    dim3 blk(256);

    // 1) Q,K,V = x @ W^T  (fused in one launch, 768 blocks = 3/CU)
    dim3 gqkv(M / BM, C / BN, 3);
    sgemm_qkv<<<gqkv, blk, 0, stream>>>(x, Wq, Wk, Wv, Qb, Kb, Vb, C, C);

    // 2) RoPE + normalize + scale (in place on Q,K)
    rope_norm<<<dim3(2 * B * T * H / 4), blk, 0, stream>>>(Qb, Kb, s_qk);

    // 3) attention -> Y in [B,T,H,D] layout (64 q-rows per block, G=4)
    attn<<<dim3(T / 64, B * H), blk, 0, stream>>>(Qb, Kb, Vb, Yb);

    // 4) out = Y @ Wo^T
    dim3 go(M / BM, C / BN);
    sgemm_one<<<go, blk, 0, stream>>>(Yb, Wo, out, C, C);
}

// Round 3
// 776.232 us; speedup vs baseline: 2.7986x; 2.2538x over previous
//
#include <hip/hip_runtime.h>
#include <math.h>

// nGPT attention. B=2, T=2048, C=1024, H=16, D=64.
// R3: MFMA flash attention. QK via bf16x3 split (logits std~1024, near-one-hot
// softmax: plain bf16 flips near-tied rows). PV in plain bf16. fp32 softmax.
// GEMMs still fp32 vector (next target).

typedef short short8 __attribute__((ext_vector_type(8)));
typedef float floatx4 __attribute__((ext_vector_type(4)));

__device__ __forceinline__ unsigned short bf16_rne(float x) {
    unsigned u = __float_as_uint(x);
    u += 0x7FFF + ((u >> 16) & 1);
    return (unsigned short)(u >> 16);
}

__device__ __forceinline__ floatx4 mfma_bf16(short8 a, short8 b, floatx4 c) {
    asm("v_mfma_f32_16x16x32_bf16 %0, %1, %2, %0" : "+v"(c) : "v"(a), "v"(b));
    return c;
}

#define BM 128
#define BN 128
#define BKK 8

// C[m][n] = sum_k A[m*K+k] * B[n*K+k]   (A @ B^T, both row-major)
__device__ __forceinline__ void sgemm_body(const float* __restrict__ A,
                                           const float* __restrict__ Bm,
                                           float* __restrict__ Cm,
                                           int K, int N, int bm, int bn)
{
    __shared__ float As[BKK][BM + 4];
    __shared__ float Bs[BKK][BN + 4];
    const int tid = threadIdx.x;
    const int lr = tid >> 1;
    const int lk = (tid & 1) << 2;
    const float* Ald = A + (size_t)(bm + lr) * K + lk;
    const float* Bld = Bm + (size_t)(bn + lr) * K + lk;
    const int tr = (tid & 15) << 3;
    const int tc = (tid >> 4) << 3;

    float acc[8][8];
#pragma unroll
    for (int i = 0; i < 8; ++i)
#pragma unroll
        for (int j = 0; j < 8; ++j) acc[i][j] = 0.f;

    for (int kt = 0; kt < K; kt += BKK) {
        float4 av = *(const float4*)(Ald + kt);
        float4 bv = *(const float4*)(Bld + kt);
        __syncthreads();
        As[lk + 0][lr] = av.x; As[lk + 1][lr] = av.y;
        As[lk + 2][lr] = av.z; As[lk + 3][lr] = av.w;
        Bs[lk + 0][lr] = bv.x; Bs[lk + 1][lr] = bv.y;
        Bs[lk + 2][lr] = bv.z; Bs[lk + 3][lr] = bv.w;
        __syncthreads();
#pragma unroll
        for (int kk = 0; kk < BKK; ++kk) {
            float a[8], b[8];
#pragma unroll
            for (int i = 0; i < 8; ++i) a[i] = As[kk][tr + i];
#pragma unroll
            for (int j = 0; j < 8; ++j) b[j] = Bs[kk][tc + j];
#pragma unroll
            for (int i = 0; i < 8; ++i)
#pragma unroll
                for (int j = 0; j < 8; ++j)
                    acc[i][j] += a[i] * b[j];
        }
    }

#pragma unroll
    for (int i = 0; i < 8; ++i) {
        float* crow = Cm + (size_t)(bm + tr + i) * N + (bn + tc);
        *(float4*)(crow)     = make_float4(acc[i][0], acc[i][1], acc[i][2], acc[i][3]);
        *(float4*)(crow + 4) = make_float4(acc[i][4], acc[i][5], acc[i][6], acc[i][7]);
    }
}

__global__ __launch_bounds__(256) void sgemm_qkv(const float* __restrict__ x,
    const float* __restrict__ Wq, const float* __restrict__ Wk,
    const float* __restrict__ Wv,
    float* __restrict__ Qo, float* __restrict__ Ko, float* __restrict__ Vo,
    int N, int K)
{
    const float* W; float* O;
    if (blockIdx.z == 0)      { W = Wq; O = Qo; }
    else if (blockIdx.z == 1) { W = Wk; O = Ko; }
    else                      { W = Wv; O = Vo; }
    sgemm_body(x, W, O, K, N, blockIdx.x * BM, blockIdx.y * BN);
}

__global__ __launch_bounds__(256) void sgemm_one(const float* __restrict__ A,
    const float* __restrict__ W, float* __restrict__ O, int N, int K)
{
    sgemm_body(A, W, O, K, N, blockIdx.x * BM, blockIdx.y * BN);
}

// One wave per (b,t,h,{q|k}); lane = d. In-place RoPE + L2-normalize + scale.
__global__ __launch_bounds__(256) void rope_norm(float* __restrict__ Q,
                                                 float* __restrict__ K,
                                                 const float* __restrict__ s_qk)
{
    constexpr int T = 2048, H = 16, D = 64;
    int wid = blockIdx.x * 4 + (threadIdx.x >> 6);
    const int lane = threadIdx.x & 63;
    const int sel = wid & 1; wid >>= 1;
    const int h = wid & (H - 1); wid >>= 4;
    const int t = wid & (T - 1); wid >>= 11;
    const int b = wid;

    float* ptr = (sel ? K : Q) + (((size_t)(b * T + t)) * H + h) * D;
    float v = ptr[lane];

    const int p = lane >> 1;
    double invf = pow(10000.0, -(double)p / 32.0);
    double sd, cd;
    sincos((double)t * invf, &sd, &cd);
    const float sn = (float)sd, cs = (float)cd;

    float partner = __shfl_xor(v, 1, 64);
    float rot = (lane & 1) ? partner : -partner;
    float r = v * cs + rot * sn;

    float ssq = r * r;
#pragma unroll
    for (int off = 32; off; off >>= 1) ssq += __shfl_xor(ssq, off, 64);
    float nrm = fmaxf(sqrtf(ssq), 1e-12f);

    float scale = s_qk[h * D + lane] * 32.0f;   // s_qk * sqrt(C)
    if (!sel) scale *= 8.0f;                    // fold sqrt(D) into Q
    ptr[lane] = r / nrm * scale;
}

// ---------------- MFMA flash attention ----------------
// Block: 256 threads = 4 waves; each wave owns a 16-row Q stripe (QTILE=64).
// Key tiles of 32. Layouts (16x16x32 bf16 mfma, m89/m120-verified):
//   A[m=lane&15][k=(lane>>4)*8+j], B[n=lane&15][k=(lane>>4)*8+j],
//   C/D: col=lane&15, row=(lane>>4)*4+reg.
#define QTILE 64
#define KTL 32
#define KS_STRIDE 72   // shorts per K row (64 + 8 pad -> 2-way bank alias, free)
#define VT_STRIDE 40   // shorts per Vt/Ps row (32 + 8 pad)

__global__ __launch_bounds__(256) void attn_mfma(const float* __restrict__ Q,
                                                 const float* __restrict__ K,
                                                 const float* __restrict__ V,
                                                 float* __restrict__ Y)
{
    constexpr int T = 2048, C = 1024;
    __shared__ __align__(16) unsigned short Ks_hi[KTL * KS_STRIDE];
    __shared__ __align__(16) unsigned short Ks_lo[KTL * KS_STRIDE];
    __shared__ __align__(16) unsigned short Vt[64 * VT_STRIDE];      // [dim][key]
    __shared__ __align__(16) unsigned short Ps[4][16 * VT_STRIDE];   // per-wave P

    const int bh = blockIdx.y;
    const int h = bh & 15;
    const int b = bh >> 4;
    const int w = threadIdx.x >> 6;
    const int lane = threadIdx.x & 63;
    const int n16 = lane & 15;
    const int quad = lane >> 4;

    const float* qb = Q + (size_t)(b * T) * C + h * 64;
    const float* kb = K + (size_t)(b * T) * C + h * 64;
    const float* vb = V + (size_t)(b * T) * C + h * 64;

    // Q A-fragments (hi/lo), 2 D-chunks, loaded once from global.
    const int qrow = blockIdx.x * QTILE + w * 16 + n16;
    short8 qh[2], ql[2];
#pragma unroll
    for (int c = 0; c < 2; ++c) {
        const float* p = qb + (size_t)qrow * C + c * 32 + quad * 8;
        float4 f0 = *(const float4*)p;
        float4 f1 = *(const float4*)(p + 4);
        float f[8] = {f0.x, f0.y, f0.z, f0.w, f1.x, f1.y, f1.z, f1.w};
#pragma unroll
        for (int j = 0; j < 8; ++j) {
            unsigned short hb = bf16_rne(f[j]);
            float hf = __uint_as_float((unsigned)hb << 16);
            qh[c][j] = (short)hb;
            ql[c][j] = (short)bf16_rne(f[j] - hf);
        }
    }

    floatx4 o0 = {0,0,0,0}, o1 = {0,0,0,0}, o2 = {0,0,0,0}, o3 = {0,0,0,0};
    float mrow[4] = {-1e30f, -1e30f, -1e30f, -1e30f};
    float lrow[4] = {0.f, 0.f, 0.f, 0.f};

    // staging assignments
    const int skey = threadIdx.x >> 3;        // 0..31
    const int sd0  = (threadIdx.x & 7) * 8;   // 0..56
    unsigned short* Pw = Ps[w];

    for (int kt = 0; kt < T; kt += KTL) {
        __syncthreads();
        // ---- stage K (hi/lo bf16) ----
        {
            const float* p = kb + (size_t)(kt + skey) * C + sd0;
            float4 f0 = *(const float4*)p;
            float4 f1 = *(const float4*)(p + 4);
            float f[8] = {f0.x, f0.y, f0.z, f0.w, f1.x, f1.y, f1.z, f1.w};
            short8 sh, sl;
#pragma unroll
            for (int j = 0; j < 8; ++j) {
                unsigned short hb = bf16_rne(f[j]);
                float hf = __uint_as_float((unsigned)hb << 16);
                sh[j] = (short)hb;
                sl[j] = (short)bf16_rne(f[j] - hf);
            }
            *(short8*)&Ks_hi[skey * KS_STRIDE + sd0] = sh;
            *(short8*)&Ks_lo[skey * KS_STRIDE + sd0] = sl;
        }
        // ---- stage V transposed: Vt[dim][key] ----
        {
            short8 vv;
#pragma unroll
            for (int i = 0; i < 8; ++i) {
                float xv = vb[(size_t)(kt + w * 8 + i) * C + lane];
                vv[i] = (short)bf16_rne(xv);
            }
            *(short8*)&Vt[lane * VT_STRIDE + w * 8] = vv;
        }
        __syncthreads();

        // ---- QK^T: 2 key sub-tiles x (2 chunks x 3 split-terms) ----
        floatx4 a0 = {0,0,0,0}, a1 = {0,0,0,0};
#pragma unroll
        for (int c = 0; c < 2; ++c) {
            const int ko = c * 32 + quad * 8;
            short8 kh0 = *(const short8*)&Ks_hi[n16 * KS_STRIDE + ko];
            short8 kl0 = *(const short8*)&Ks_lo[n16 * KS_STRIDE + ko];
            short8 kh1 = *(const short8*)&Ks_hi[(16 + n16) * KS_STRIDE + ko];
            short8 kl1 = *(const short8*)&Ks_lo[(16 + n16) * KS_STRIDE + ko];
            a0 = mfma_bf16(qh[c], kh0, a0);
            a0 = mfma_bf16(qh[c], kl0, a0);
            a0 = mfma_bf16(ql[c], kh0, a0);
            a1 = mfma_bf16(qh[c], kh1, a1);
            a1 = mfma_bf16(qh[c], kl1, a1);
            a1 = mfma_bf16(ql[c], kh1, a1);
        }

        // ---- online softmax (fp32, C-layout) + P -> LDS (bf16) ----
#pragma unroll
        for (int r = 0; r < 4; ++r) {
            float mx = fmaxf(a0[r], a1[r]);
            mx = fmaxf(mx, __shfl_xor(mx, 1, 64));
            mx = fmaxf(mx, __shfl_xor(mx, 2, 64));
            mx = fmaxf(mx, __shfl_xor(mx, 4, 64));
            mx = fmaxf(mx, __shfl_xor(mx, 8, 64));
            float mn = fmaxf(mrow[r], mx);
            float fac = __expf(mrow[r] - mn);
            mrow[r] = mn;
            float p0 = __expf(a0[r] - mn);
            float p1 = __expf(a1[r] - mn);
            float s = p0 + p1;
            s += __shfl_xor(s, 1, 64);
            s += __shfl_xor(s, 2, 64);
            s += __shfl_xor(s, 4, 64);
            s += __shfl_xor(s, 8, 64);
            lrow[r] = lrow[r] * fac + s;
            o0[r] *= fac; o1[r] *= fac; o2[r] *= fac; o3[r] *= fac;
            Pw[(quad * 4 + r) * VT_STRIDE + n16]      = bf16_rne(p0);
            Pw[(quad * 4 + r) * VT_STRIDE + 16 + n16] = bf16_rne(p1);
        }

        // ---- PV: P (A-layout via LDS) x Vt (B-layout) ----
        {
            short8 pa = *(const short8*)&Pw[n16 * VT_STRIDE + quad * 8];
            short8 v0 = *(const short8*)&Vt[n16 * VT_STRIDE + quad * 8];
            short8 v1 = *(const short8*)&Vt[(16 + n16) * VT_STRIDE + quad * 8];
            short8 v2 = *(const short8*)&Vt[(32 + n16) * VT_STRIDE + quad * 8];
            short8 v3 = *(const short8*)&Vt[(48 + n16) * VT_STRIDE + quad * 8];
            o0 = mfma_bf16(pa, v0, o0);
            o1 = mfma_bf16(pa, v1, o1);
            o2 = mfma_bf16(pa, v2, o2);
            o3 = mfma_bf16(pa, v3, o3);
        }
    }

    // ---- epilogue: normalize, write Y ----
#pragma unroll
    for (int r = 0; r < 4; ++r) {
        float inv = 1.0f / lrow[r];
        int row = blockIdx.x * QTILE + w * 16 + quad * 4 + r;
        float* yp = Y + (size_t)(b * T + row) * C + h * 64 + n16;
        yp[0]  = o0[r] * inv;
        yp[16] = o1[r] * inv;
        yp[32] = o2[r] * inv;
        yp[48] = o3[r] * inv;
    }
}

extern "C" void kernel_launch(void* const* d_in, const int* in_sizes, int n_in,
                              void* d_out, int out_size, void* d_ws, size_t ws_size,
                              hipStream_t stream)
{
    const float* x    = (const float*)d_in[0];
    const float* Wq   = (const float*)d_in[1];
    const float* Wk   = (const float*)d_in[2];
    const float* Wv   = (const float*)d_in[3];
    const float* Wo   = (const float*)d_in[4];
    const float* s_qk = (const float*)d_in[5];
    float* out = (float*)d_out;

    constexpr int B = 2, T = 2048, C = 1024, H = 16;
    constexpr int M = B * T;
    const size_t mat = (size_t)M * C;

    float* Qb = (float*)d_ws;
    float* Kb = Qb + mat;
    float* Vb = Kb + mat;
    float* Yb = Vb + mat;

    dim3 blk(256);

    dim3 gqkv(M / BM, C / BN, 3);
    sgemm_qkv<<<gqkv, blk, 0, stream>>>(x, Wq, Wk, Wv, Qb, Kb, Vb, C, C);

    rope_norm<<<dim3(2 * B * T * H / 4), blk, 0, stream>>>(Qb, Kb, s_qk);

    attn_mfma<<<dim3(T / QTILE, B * H), blk, 0, stream>>>(Qb, Kb, Vb, Yb);

    dim3 go(M / BM, C / BN);
    sgemm_one<<<go, blk, 0, stream>>>(Yb, Wo, out, C, C);
}

// Round 4
// 427.820 us; speedup vs baseline: 5.0777x; 1.8144x over previous
//
#include <hip/hip_runtime.h>
#include <math.h>

// nGPT attention. B=2, T=2048, C=1024, H=16, D=64.
// R4: all GEMMs on MFMA. Q/K projections use bf16x3 split (their error is
// amplified ~1024x into logits via normalize->dot); V/Wo plain bf16 (error
// lands directly on output, ~0.002). RoPE cos/sin via small DP table kernel
// (was per-thread double pow+sincos). attn_mfma unchanged from R3.

typedef short short8 __attribute__((ext_vector_type(8)));
typedef float floatx4 __attribute__((ext_vector_type(4)));

__device__ __forceinline__ unsigned short bf16_rne(float x) {
    unsigned u = __float_as_uint(x);
    u += 0x7FFF + ((u >> 16) & 1);
    return (unsigned short)(u >> 16);
}

__device__ __forceinline__ floatx4 mfma_bf16(short8 a, short8 b, floatx4 c) {
    asm("v_mfma_f32_16x16x32_bf16 %0, %1, %2, %0" : "+v"(c) : "v"(a), "v"(b));
    return c;
}

// ---------------- MFMA GEMM: C[m][n] = sum_k A[m][k] * W[n][k] ----------------
// 128x128 tile, BK=32, 4 waves each computing a 64x64 quadrant (4x4 frags of
// 16x16x32). fp32 inputs converted to bf16 hi(/lo) during LDS staging.
// TERMS=3: bf16x3 split (ah*bh + ah*bl + al*bh). TERMS=1: plain bf16.
#define LSTR 40   // shorts per LDS row (32 + 8 pad; 80B rows -> <=2-way alias)

template<int TERMS>
__device__ __forceinline__ void mgemm_body(unsigned short* lds,
                                           const float* __restrict__ A,
                                           const float* __restrict__ W,
                                           float* __restrict__ Cm,
                                           int bm, int bn)
{
    constexpr int Kd = 1024, Nd = 1024;
    unsigned short* Ah = lds;
    unsigned short* Wh = lds + 128 * LSTR;
    unsigned short* Al = lds + 2 * 128 * LSTR;
    unsigned short* Wl = lds + 3 * 128 * LSTR;

    const int tid = threadIdx.x;
    const int srow = tid >> 1;            // 0..127
    const int skc = (tid & 1) << 4;       // 0 or 16
    const float* Ald = A + (size_t)(bm + srow) * Kd + skc;
    const float* Wld = W + (size_t)(bn + srow) * Kd + skc;

    const int lane = tid & 63;
    const int w = tid >> 6;
    const int n16 = lane & 15;
    const int quad = lane >> 4;
    const int m0 = (w & 1) << 6;
    const int n0 = (w >> 1) << 6;

    floatx4 acc[4][4];
#pragma unroll
    for (int j = 0; j < 4; ++j)
#pragma unroll
        for (int i = 0; i < 4; ++i) acc[j][i] = (floatx4){0.f, 0.f, 0.f, 0.f};

    for (int kt = 0; kt < Kd; kt += 32) {
        float fa[16], fw[16];
#pragma unroll
        for (int q4 = 0; q4 < 4; ++q4) {
            *(float4*)&fa[q4 * 4] = *(const float4*)(Ald + kt + q4 * 4);
            *(float4*)&fw[q4 * 4] = *(const float4*)(Wld + kt + q4 * 4);
        }
        __syncthreads();   // previous iter's frag reads done
        {
            short8 h, l;
#pragma unroll
            for (int half = 0; half < 2; ++half) {
#pragma unroll
                for (int j = 0; j < 8; ++j) {
                    float xv = fa[half * 8 + j];
                    unsigned short hb = bf16_rne(xv);
                    h[j] = (short)hb;
                    if (TERMS == 3)
                        l[j] = (short)bf16_rne(xv - __uint_as_float((unsigned)hb << 16));
                }
                *(short8*)&Ah[srow * LSTR + skc + half * 8] = h;
                if (TERMS == 3) *(short8*)&Al[srow * LSTR + skc + half * 8] = l;
            }
#pragma unroll
            for (int half = 0; half < 2; ++half) {
#pragma unroll
                for (int j = 0; j < 8; ++j) {
                    float xv = fw[half * 8 + j];
                    unsigned short hb = bf16_rne(xv);
                    h[j] = (short)hb;
                    if (TERMS == 3)
                        l[j] = (short)bf16_rne(xv - __uint_as_float((unsigned)hb << 16));
                }
                *(short8*)&Wh[srow * LSTR + skc + half * 8] = h;
                if (TERMS == 3) *(short8*)&Wl[srow * LSTR + skc + half * 8] = l;
            }
        }
        __syncthreads();

        short8 ah[4], al[4];
#pragma unroll
        for (int i = 0; i < 4; ++i) {
            ah[i] = *(const short8*)&Ah[(m0 + i * 16 + n16) * LSTR + quad * 8];
            if (TERMS == 3)
                al[i] = *(const short8*)&Al[(m0 + i * 16 + n16) * LSTR + quad * 8];
        }
#pragma unroll
        for (int j = 0; j < 4; ++j) {
            short8 bh = *(const short8*)&Wh[(n0 + j * 16 + n16) * LSTR + quad * 8];
#pragma unroll
            for (int i = 0; i < 4; ++i)
                acc[j][i] = mfma_bf16(ah[i], bh, acc[j][i]);
            if (TERMS == 3) {
                short8 bl = *(const short8*)&Wl[(n0 + j * 16 + n16) * LSTR + quad * 8];
#pragma unroll
                for (int i = 0; i < 4; ++i) {
                    acc[j][i] = mfma_bf16(ah[i], bl, acc[j][i]);
                    acc[j][i] = mfma_bf16(al[i], bh, acc[j][i]);
                }
            }
        }
    }

    // epilogue: C/D layout col=n16, row=quad*4+r
#pragma unroll
    for (int j = 0; j < 4; ++j)
#pragma unroll
        for (int i = 0; i < 4; ++i) {
            float* cp = Cm + (size_t)(bm + m0 + i * 16 + quad * 4) * Nd
                        + bn + n0 + j * 16 + n16;
#pragma unroll
            for (int r = 0; r < 4; ++r)
                cp[(size_t)r * Nd] = acc[j][i][r];
        }
}

__global__ __launch_bounds__(256) void mgemm_qkv(const float* __restrict__ x,
    const float* __restrict__ Wq, const float* __restrict__ Wk,
    const float* __restrict__ Wv,
    float* __restrict__ Qo, float* __restrict__ Ko, float* __restrict__ Vo)
{
    __shared__ __align__(16) unsigned short lds[4 * 128 * LSTR];   // 40 KB
    const int bm = blockIdx.x * 128, bn = blockIdx.y * 128;
    if (blockIdx.z == 2) {
        mgemm_body<1>(lds, x, Wv, Vo, bm, bn);
    } else {
        const float* W = (blockIdx.z == 0) ? Wq : Wk;
        float* O = (blockIdx.z == 0) ? Qo : Ko;
        mgemm_body<3>(lds, x, W, O, bm, bn);
    }
}

__global__ __launch_bounds__(256) void mgemm_o(const float* __restrict__ A,
    const float* __restrict__ W, float* __restrict__ O)
{
    __shared__ __align__(16) unsigned short lds[2 * 128 * LSTR];   // 20 KB
    mgemm_body<1>(lds, A, W, O, blockIdx.x * 128, blockIdx.y * 128);
}

// ---------------- RoPE ----------------
// Table: cos/sin for all (t, p) pairs in double, once. 65536 entries.
__global__ __launch_bounds__(256) void rope_table(float2* __restrict__ tab)
{
    int idx = blockIdx.x * 256 + threadIdx.x;   // t*32 + p
    int t = idx >> 5, p = idx & 31;
    double invf = pow(10000.0, -(double)p / 32.0);
    double sd, cd;
    sincos((double)t * invf, &sd, &cd);
    tab[idx] = make_float2((float)cd, (float)sd);
}

// One wave per (b,t,h,{q|k}); lane = d. In-place RoPE + L2-normalize + scale.
__global__ __launch_bounds__(256) void rope_norm(float* __restrict__ Q,
                                                 float* __restrict__ K,
                                                 const float* __restrict__ s_qk,
                                                 const float2* __restrict__ tab)
{
    constexpr int T = 2048, H = 16, D = 64;
    int wid = blockIdx.x * 4 + (threadIdx.x >> 6);
    const int lane = threadIdx.x & 63;
    const int sel = wid & 1; wid >>= 1;
    const int h = wid & (H - 1); wid >>= 4;
    const int t = wid & (T - 1); wid >>= 11;
    const int b = wid;

    float* ptr = (sel ? K : Q) + (((size_t)(b * T + t)) * H + h) * D;
    float v = ptr[lane];

    float2 cs2 = tab[(t << 5) + (lane >> 1)];
    const float cs = cs2.x, sn = cs2.y;

    float partner = __shfl_xor(v, 1, 64);
    float rot = (lane & 1) ? partner : -partner;
    float r = v * cs + rot * sn;

    float ssq = r * r;
#pragma unroll
    for (int off = 32; off; off >>= 1) ssq += __shfl_xor(ssq, off, 64);
    float nrm = fmaxf(sqrtf(ssq), 1e-12f);

    float scale = s_qk[h * D + lane] * 32.0f;   // s_qk * sqrt(C)
    if (!sel) scale *= 8.0f;                    // fold sqrt(D) into Q
    ptr[lane] = r / nrm * scale;
}

// ---------------- MFMA flash attention (unchanged from R3) ----------------
#define QTILE 64
#define KTL 32
#define KS_STRIDE 72
#define VT_STRIDE 40

__global__ __launch_bounds__(256) void attn_mfma(const float* __restrict__ Q,
                                                 const float* __restrict__ K,
                                                 const float* __restrict__ V,
                                                 float* __restrict__ Y)
{
    constexpr int T = 2048, C = 1024;
    __shared__ __align__(16) unsigned short Ks_hi[KTL * KS_STRIDE];
    __shared__ __align__(16) unsigned short Ks_lo[KTL * KS_STRIDE];
    __shared__ __align__(16) unsigned short Vt[64 * VT_STRIDE];
    __shared__ __align__(16) unsigned short Ps[4][16 * VT_STRIDE];

    const int bh = blockIdx.y;
    const int h = bh & 15;
    const int b = bh >> 4;
    const int w = threadIdx.x >> 6;
    const int lane = threadIdx.x & 63;
    const int n16 = lane & 15;
    const int quad = lane >> 4;

    const float* qb = Q + (size_t)(b * T) * C + h * 64;
    const float* kb = K + (size_t)(b * T) * C + h * 64;
    const float* vb = V + (size_t)(b * T) * C + h * 64;

    const int qrow = blockIdx.x * QTILE + w * 16 + n16;
    short8 qh[2], ql[2];
#pragma unroll
    for (int c = 0; c < 2; ++c) {
        const float* p = qb + (size_t)qrow * C + c * 32 + quad * 8;
        float4 f0 = *(const float4*)p;
        float4 f1 = *(const float4*)(p + 4);
        float f[8] = {f0.x, f0.y, f0.z, f0.w, f1.x, f1.y, f1.z, f1.w};
#pragma unroll
        for (int j = 0; j < 8; ++j) {
            unsigned short hb = bf16_rne(f[j]);
            float hf = __uint_as_float((unsigned)hb << 16);
            qh[c][j] = (short)hb;
            ql[c][j] = (short)bf16_rne(f[j] - hf);
        }
    }

    floatx4 o0 = {0,0,0,0}, o1 = {0,0,0,0}, o2 = {0,0,0,0}, o3 = {0,0,0,0};
    float mrow[4] = {-1e30f, -1e30f, -1e30f, -1e30f};
    float lrow[4] = {0.f, 0.f, 0.f, 0.f};

    const int skey = threadIdx.x >> 3;
    const int sd0  = (threadIdx.x & 7) * 8;
    unsigned short* Pw = Ps[w];

    for (int kt = 0; kt < T; kt += KTL) {
        __syncthreads();
        {
            const float* p = kb + (size_t)(kt + skey) * C + sd0;
            float4 f0 = *(const float4*)p;
            float4 f1 = *(const float4*)(p + 4);
            float f[8] = {f0.x, f0.y, f0.z, f0.w, f1.x, f1.y, f1.z, f1.w};
            short8 sh, sl;
#pragma unroll
            for (int j = 0; j < 8; ++j) {
                unsigned short hb = bf16_rne(f[j]);
                float hf = __uint_as_float((unsigned)hb << 16);
                sh[j] = (short)hb;
                sl[j] = (short)bf16_rne(f[j] - hf);
            }
            *(short8*)&Ks_hi[skey * KS_STRIDE + sd0] = sh;
            *(short8*)&Ks_lo[skey * KS_STRIDE + sd0] = sl;
        }
        {
            short8 vv;
#pragma unroll
            for (int i = 0; i < 8; ++i) {
                float xv = vb[(size_t)(kt + w * 8 + i) * C + lane];
                vv[i] = (short)bf16_rne(xv);
            }
            *(short8*)&Vt[lane * VT_STRIDE + w * 8] = vv;
        }
        __syncthreads();

        floatx4 a0 = {0,0,0,0}, a1 = {0,0,0,0};
#pragma unroll
        for (int c = 0; c < 2; ++c) {
            const int ko = c * 32 + quad * 8;
            short8 kh0 = *(const short8*)&Ks_hi[n16 * KS_STRIDE + ko];
            short8 kl0 = *(const short8*)&Ks_lo[n16 * KS_STRIDE + ko];
            short8 kh1 = *(const short8*)&Ks_hi[(16 + n16) * KS_STRIDE + ko];
            short8 kl1 = *(const short8*)&Ks_lo[(16 + n16) * KS_STRIDE + ko];
            a0 = mfma_bf16(qh[c], kh0, a0);
            a0 = mfma_bf16(qh[c], kl0, a0);
            a0 = mfma_bf16(ql[c], kh0, a0);
            a1 = mfma_bf16(qh[c], kh1, a1);
            a1 = mfma_bf16(qh[c], kl1, a1);
            a1 = mfma_bf16(ql[c], kh1, a1);
        }

#pragma unroll
        for (int r = 0; r < 4; ++r) {
            float mx = fmaxf(a0[r], a1[r]);
            mx = fmaxf(mx, __shfl_xor(mx, 1, 64));
            mx = fmaxf(mx, __shfl_xor(mx, 2, 64));
            mx = fmaxf(mx, __shfl_xor(mx, 4, 64));
            mx = fmaxf(mx, __shfl_xor(mx, 8, 64));
            float mn = fmaxf(mrow[r], mx);
            float fac = __expf(mrow[r] - mn);
            mrow[r] = mn;
            float p0 = __expf(a0[r] - mn);
            float p1 = __expf(a1[r] - mn);
            float s = p0 + p1;
            s += __shfl_xor(s, 1, 64);
            s += __shfl_xor(s, 2, 64);
            s += __shfl_xor(s, 4, 64);
            s += __shfl_xor(s, 8, 64);
            lrow[r] = lrow[r] * fac + s;
            o0[r] *= fac; o1[r] *= fac; o2[r] *= fac; o3[r] *= fac;
            Pw[(quad * 4 + r) * VT_STRIDE + n16]      = bf16_rne(p0);
            Pw[(quad * 4 + r) * VT_STRIDE + 16 + n16] = bf16_rne(p1);
        }

        {
            short8 pa = *(const short8*)&Pw[n16 * VT_STRIDE + quad * 8];
            short8 v0 = *(const short8*)&Vt[n16 * VT_STRIDE + quad * 8];
            short8 v1 = *(const short8*)&Vt[(16 + n16) * VT_STRIDE + quad * 8];
            short8 v2 = *(const short8*)&Vt[(32 + n16) * VT_STRIDE + quad * 8];
            short8 v3 = *(const short8*)&Vt[(48 + n16) * VT_STRIDE + quad * 8];
            o0 = mfma_bf16(pa, v0, o0);
            o1 = mfma_bf16(pa, v1, o1);
            o2 = mfma_bf16(pa, v2, o2);
            o3 = mfma_bf16(pa, v3, o3);
        }
    }

#pragma unroll
    for (int r = 0; r < 4; ++r) {
        float inv = 1.0f / lrow[r];
        int row = blockIdx.x * QTILE + w * 16 + quad * 4 + r;
        float* yp = Y + (size_t)(b * T + row) * C + h * 64 + n16;
        yp[0]  = o0[r] * inv;
        yp[16] = o1[r] * inv;
        yp[32] = o2[r] * inv;
        yp[48] = o3[r] * inv;
    }
}

extern "C" void kernel_launch(void* const* d_in, const int* in_sizes, int n_in,
                              void* d_out, int out_size, void* d_ws, size_t ws_size,
                              hipStream_t stream)
{
    const float* x    = (const float*)d_in[0];
    const float* Wq   = (const float*)d_in[1];
    const float* Wk   = (const float*)d_in[2];
    const float* Wv   = (const float*)d_in[3];
    const float* Wo   = (const float*)d_in[4];
    const float* s_qk = (const float*)d_in[5];
    float* out = (float*)d_out;

    constexpr int B = 2, T = 2048, C = 1024, H = 16;
    constexpr int M = B * T;
    const size_t mat = (size_t)M * C;

    float* Qb = (float*)d_ws;
    float* Kb = Qb + mat;
    float* Vb = Kb + mat;
    float* Yb = Vb + mat;
    float2* tab = (float2*)Yb;   // Y region unused until attn; table read before

    dim3 blk(256);

    rope_table<<<dim3(T * 32 / 256), blk, 0, stream>>>(tab);
    mgemm_qkv<<<dim3(M / 128, C / 128, 3), blk, 0, stream>>>(x, Wq, Wk, Wv, Qb, Kb, Vb);
    rope_norm<<<dim3(2 * B * T * H / 4), blk, 0, stream>>>(Qb, Kb, s_qk, tab);
    attn_mfma<<<dim3(T / QTILE, B * H), blk, 0, stream>>>(Qb, Kb, Vb, Yb);
    mgemm_o<<<dim3(M / 128, C / 128), blk, 0, stream>>>(Yb, Wo, out);
}

// Round 5
// 373.964 us; speedup vs baseline: 5.8089x; 1.1440x over previous
//
#include <hip/hip_runtime.h>
#include <math.h>

// nGPT attention. B=2, T=2048, C=1024, H=16, D=64.
// R5: attn DS-pipe relief: (1) softmax reductions on DPP (VALU) instead of
// ds_swizzle, (2) K pre-split to bf16 hi/lo by rope_norm (in-place over its
// own fp32 row; wave-lockstep makes this safe), (3) V pre-transposed to bf16
// vt[bh][d][t] by a small kernel; mgemm writes V directly as bf16.
// Q/K projections stay bf16x3 (logit error amplified ~1024x); V/Wo plain bf16.

typedef short short8 __attribute__((ext_vector_type(8)));
typedef float floatx4 __attribute__((ext_vector_type(4)));

__device__ __forceinline__ unsigned short bf16_rne(float x) {
    unsigned u = __float_as_uint(x);
    u += 0x7FFF + ((u >> 16) & 1);
    return (unsigned short)(u >> 16);
}

__device__ __forceinline__ floatx4 mfma_bf16(short8 a, short8 b, floatx4 c) {
    asm("v_mfma_f32_16x16x32_bf16 %0, %1, %2, %0" : "+v"(c) : "v"(a), "v"(b));
    return c;
}

// ---- DPP 16-lane butterfly reductions (VALU, not DS pipe) ----
// groups = DPP rows (16 contiguous lanes). Steps: xor1, xor2, mirror-in-8
// (combines quads), mirror-in-16 (combines halves).
template<int CTRL>
__device__ __forceinline__ float dpp_mov_f(float x) {
    return __int_as_float(__builtin_amdgcn_update_dpp(
        __float_as_int(x), __float_as_int(x), CTRL, 0xF, 0xF, false));
}
__device__ __forceinline__ float row_max16(float x) {
    x = fmaxf(x, dpp_mov_f<0xB1>(x));    // quad_perm(1,0,3,2)
    x = fmaxf(x, dpp_mov_f<0x4E>(x));    // quad_perm(2,3,0,1)
    x = fmaxf(x, dpp_mov_f<0x141>(x));   // row_half_mirror
    x = fmaxf(x, dpp_mov_f<0x140>(x));   // row_mirror
    return x;
}
__device__ __forceinline__ float row_sum16(float x) {
    x += dpp_mov_f<0xB1>(x);
    x += dpp_mov_f<0x4E>(x);
    x += dpp_mov_f<0x141>(x);
    x += dpp_mov_f<0x140>(x);
    return x;
}

// ---------------- MFMA GEMM: C[m][n] = sum_k A[m][k] * W[n][k] ----------------
#define LSTR 40   // shorts per LDS row (32 + 8 pad)

template<int TERMS, bool OUT16>
__device__ __forceinline__ void mgemm_body(unsigned short* lds,
                                           const float* __restrict__ A,
                                           const float* __restrict__ W,
                                           void* __restrict__ Cm,
                                           int bm, int bn)
{
    constexpr int Kd = 1024, Nd = 1024;
    unsigned short* Ah = lds;
    unsigned short* Wh = lds + 128 * LSTR;
    unsigned short* Al = lds + 2 * 128 * LSTR;
    unsigned short* Wl = lds + 3 * 128 * LSTR;

    const int tid = threadIdx.x;
    const int srow = tid >> 1;
    const int skc = (tid & 1) << 4;
    const float* Ald = A + (size_t)(bm + srow) * Kd + skc;
    const float* Wld = W + (size_t)(bn + srow) * Kd + skc;

    const int lane = tid & 63;
    const int w = tid >> 6;
    const int n16 = lane & 15;
    const int quad = lane >> 4;
    const int m0 = (w & 1) << 6;
    const int n0 = (w >> 1) << 6;

    floatx4 acc[4][4];
#pragma unroll
    for (int j = 0; j < 4; ++j)
#pragma unroll
        for (int i = 0; i < 4; ++i) acc[j][i] = (floatx4){0.f, 0.f, 0.f, 0.f};

    for (int kt = 0; kt < Kd; kt += 32) {
        float fa[16], fw[16];
#pragma unroll
        for (int q4 = 0; q4 < 4; ++q4) {
            *(float4*)&fa[q4 * 4] = *(const float4*)(Ald + kt + q4 * 4);
            *(float4*)&fw[q4 * 4] = *(const float4*)(Wld + kt + q4 * 4);
        }
        __syncthreads();
        {
            short8 h, l;
#pragma unroll
            for (int half = 0; half < 2; ++half) {
#pragma unroll
                for (int j = 0; j < 8; ++j) {
                    float xv = fa[half * 8 + j];
                    unsigned short hb = bf16_rne(xv);
                    h[j] = (short)hb;
                    if (TERMS == 3)
                        l[j] = (short)bf16_rne(xv - __uint_as_float((unsigned)hb << 16));
                }
                *(short8*)&Ah[srow * LSTR + skc + half * 8] = h;
                if (TERMS == 3) *(short8*)&Al[srow * LSTR + skc + half * 8] = l;
            }
#pragma unroll
            for (int half = 0; half < 2; ++half) {
#pragma unroll
                for (int j = 0; j < 8; ++j) {
                    float xv = fw[half * 8 + j];
                    unsigned short hb = bf16_rne(xv);
                    h[j] = (short)hb;
                    if (TERMS == 3)
                        l[j] = (short)bf16_rne(xv - __uint_as_float((unsigned)hb << 16));
                }
                *(short8*)&Wh[srow * LSTR + skc + half * 8] = h;
                if (TERMS == 3) *(short8*)&Wl[srow * LSTR + skc + half * 8] = l;
            }
        }
        __syncthreads();

        short8 ah[4], al[4];
#pragma unroll
        for (int i = 0; i < 4; ++i) {
            ah[i] = *(const short8*)&Ah[(m0 + i * 16 + n16) * LSTR + quad * 8];
            if (TERMS == 3)
                al[i] = *(const short8*)&Al[(m0 + i * 16 + n16) * LSTR + quad * 8];
        }
#pragma unroll
        for (int j = 0; j < 4; ++j) {
            short8 bh = *(const short8*)&Wh[(n0 + j * 16 + n16) * LSTR + quad * 8];
#pragma unroll
            for (int i = 0; i < 4; ++i)
                acc[j][i] = mfma_bf16(ah[i], bh, acc[j][i]);
            if (TERMS == 3) {
                short8 bl = *(const short8*)&Wl[(n0 + j * 16 + n16) * LSTR + quad * 8];
#pragma unroll
                for (int i = 0; i < 4; ++i) {
                    acc[j][i] = mfma_bf16(ah[i], bl, acc[j][i]);
                    acc[j][i] = mfma_bf16(al[i], bh, acc[j][i]);
                }
            }
        }
    }

#pragma unroll
    for (int j = 0; j < 4; ++j)
#pragma unroll
        for (int i = 0; i < 4; ++i) {
            size_t base = (size_t)(bm + m0 + i * 16 + quad * 4) * Nd
                          + bn + n0 + j * 16 + n16;
            if (OUT16) {
                unsigned short* cp = (unsigned short*)Cm + base;
#pragma unroll
                for (int r = 0; r < 4; ++r)
                    cp[(size_t)r * Nd] = bf16_rne(acc[j][i][r]);
            } else {
                float* cp = (float*)Cm + base;
#pragma unroll
                for (int r = 0; r < 4; ++r)
                    cp[(size_t)r * Nd] = acc[j][i][r];
            }
        }
}

__global__ __launch_bounds__(256) void mgemm_qkv(const float* __restrict__ x,
    const float* __restrict__ Wq, const float* __restrict__ Wk,
    const float* __restrict__ Wv,
    float* __restrict__ Qo, float* __restrict__ Ko, unsigned short* __restrict__ Vo)
{
    __shared__ __align__(16) unsigned short lds[4 * 128 * LSTR];   // 40 KB
    const int bm = blockIdx.x * 128, bn = blockIdx.y * 128;
    if (blockIdx.z == 2) {
        mgemm_body<1, true>(lds, x, Wv, Vo, bm, bn);
    } else {
        const float* W = (blockIdx.z == 0) ? Wq : Wk;
        float* O = (blockIdx.z == 0) ? Qo : Ko;
        mgemm_body<3, false>(lds, x, W, O, bm, bn);
    }
}

__global__ __launch_bounds__(256) void mgemm_o(const float* __restrict__ A,
    const float* __restrict__ W, float* __restrict__ O)
{
    __shared__ __align__(16) unsigned short lds[2 * 128 * LSTR];   // 20 KB
    mgemm_body<1, false>(lds, A, W, O, blockIdx.x * 128, blockIdx.y * 128);
}

// ---------------- RoPE ----------------
__global__ __launch_bounds__(256) void rope_table(float2* __restrict__ tab)
{
    int idx = blockIdx.x * 256 + threadIdx.x;   // t*32 + p
    int t = idx >> 5, p = idx & 31;
    double invf = pow(10000.0, -(double)p / 32.0);
    double sd, cd;
    sincos((double)t * invf, &sd, &cd);
    tab[idx] = make_float2((float)cd, (float)sd);
}

// One wave per (b,t,h,{q|k}); lane = d. RoPE + L2-normalize + scale.
// Q: in-place fp32. K: write bf16 hi|lo (128 ushorts) over its own fp32 row.
// Safe: the wave reads its whole row before any lane writes (lockstep).
__global__ __launch_bounds__(256) void rope_norm(float* __restrict__ Q,
                                                 unsigned short* __restrict__ Khl,
                                                 const float* __restrict__ s_qk,
                                                 const float2* __restrict__ tab)
{
    constexpr int T = 2048, H = 16;
    int wid = blockIdx.x * 4 + (threadIdx.x >> 6);
    const int lane = threadIdx.x & 63;
    const int sel = wid & 1; wid >>= 1;
    const int h = wid & (H - 1); wid >>= 4;
    const int t = wid & (T - 1); wid >>= 11;
    const int b = wid;

    const size_t idx = ((size_t)(b * T + t)) * H + h;
    float v = sel ? ((const float*)Khl)[idx * 64 + lane] : Q[idx * 64 + lane];

    float2 cs2 = tab[(t << 5) + (lane >> 1)];
    const float cs = cs2.x, sn = cs2.y;

    float partner = __shfl_xor(v, 1, 64);
    float rot = (lane & 1) ? partner : -partner;
    float r = v * cs + rot * sn;

    float ssq = r * r;
#pragma unroll
    for (int off = 32; off; off >>= 1) ssq += __shfl_xor(ssq, off, 64);
    float nrm = fmaxf(sqrtf(ssq), 1e-12f);

    float scale = s_qk[h * 64 + lane] * 32.0f;   // s_qk * sqrt(C)
    if (!sel) {
        float val = r / nrm * (scale * 8.0f);    // fold sqrt(D) into Q
        Q[idx * 64 + lane] = val;
    } else {
        float val = r / nrm * scale;
        unsigned short hi = bf16_rne(val);
        float hf = __uint_as_float((unsigned)hi << 16);
        unsigned short lo = bf16_rne(val - hf);
        unsigned short* row = Khl + idx * 128;
        row[lane] = hi;
        row[64 + lane] = lo;
    }
}

// ---------------- V transpose: Vbf[t][h*64+d] -> vt[bh][d][t] (bf16) --------
__global__ __launch_bounds__(256) void vtrans(const unsigned short* __restrict__ Vbf,
                                              unsigned short* __restrict__ vt)
{
    constexpr int T = 2048, C = 1024;
    __shared__ unsigned short tile[64 * 72];
    const int bh = blockIdx.y;
    const int h = bh & 15, b = bh >> 4;
    const int t0 = blockIdx.x * 64;

    const int tl = threadIdx.x & 63;        // t within tile
    const int dc = threadIdx.x >> 6;        // d chunk (16 each)
    const unsigned short* src = Vbf + (size_t)(b * T + t0 + tl) * C + h * 64 + dc * 16;
    short8 s0 = *(const short8*)src;
    short8 s1 = *(const short8*)(src + 8);
#pragma unroll
    for (int j = 0; j < 8; ++j) tile[(dc * 16 + j) * 72 + tl] = (unsigned short)s0[j];
#pragma unroll
    for (int j = 0; j < 8; ++j) tile[(dc * 16 + 8 + j) * 72 + tl] = (unsigned short)s1[j];
    __syncthreads();

    const int d = threadIdx.x >> 2;         // 0..63
    const int tc = threadIdx.x & 3;         // 16-key chunk
    short8 r0 = *(const short8*)&tile[d * 72 + tc * 16];
    short8 r1 = *(const short8*)&tile[d * 72 + tc * 16 + 8];
    unsigned short* dst = vt + ((size_t)bh * 64 + d) * T + t0 + tc * 16;
    *(short8*)dst = r0;
    *(short8*)(dst + 8) = r1;
}

// ---------------- MFMA flash attention ----------------
#define QTILE 64
#define KTL 32
#define KS_STRIDE 72
#define VT_STRIDE 40

__global__ __launch_bounds__(256) void attn_mfma(const float* __restrict__ Q,
                                                 const unsigned short* __restrict__ Khl,
                                                 const unsigned short* __restrict__ vt,
                                                 float* __restrict__ Y)
{
    constexpr int T = 2048, C = 1024;
    __shared__ __align__(16) unsigned short Ks_hi[KTL * KS_STRIDE];
    __shared__ __align__(16) unsigned short Ks_lo[KTL * KS_STRIDE];
    __shared__ __align__(16) unsigned short Vt[64 * VT_STRIDE];
    __shared__ __align__(16) unsigned short Ps[4][16 * VT_STRIDE];

    const int bh = blockIdx.y;
    const int h = bh & 15;
    const int b = bh >> 4;
    const int w = threadIdx.x >> 6;
    const int lane = threadIdx.x & 63;
    const int n16 = lane & 15;
    const int quad = lane >> 4;

    // Q A-fragments (hi/lo), loaded once and split.
    const int qrow = blockIdx.x * QTILE + w * 16 + n16;
    short8 qh[2], ql[2];
#pragma unroll
    for (int c = 0; c < 2; ++c) {
        const float* p = Q + ((size_t)(b * T + qrow)) * C + h * 64 + c * 32 + quad * 8;
        float4 f0 = *(const float4*)p;
        float4 f1 = *(const float4*)(p + 4);
        float f[8] = {f0.x, f0.y, f0.z, f0.w, f1.x, f1.y, f1.z, f1.w};
#pragma unroll
        for (int j = 0; j < 8; ++j) {
            unsigned short hb = bf16_rne(f[j]);
            float hf = __uint_as_float((unsigned)hb << 16);
            qh[c][j] = (short)hb;
            ql[c][j] = (short)bf16_rne(f[j] - hf);
        }
    }

    floatx4 o0 = {0,0,0,0}, o1 = {0,0,0,0}, o2 = {0,0,0,0}, o3 = {0,0,0,0};
    float mrow[4] = {-1e30f, -1e30f, -1e30f, -1e30f};
    float lrow[4] = {0.f, 0.f, 0.f, 0.f};

    // staging maps
    const unsigned short* khl = Khl + (((size_t)b * T) * 16 + h) * 128;
    const unsigned short* vtb = vt + (size_t)bh * 64 * T;
    const int skey = threadIdx.x >> 3;      // 0..31
    const int kch  = threadIdx.x & 7;       // 8-short chunk
    const int vd   = threadIdx.x >> 2;      // 0..63
    const int vch  = threadIdx.x & 3;       // 8-key chunk
    unsigned short* Pw = Ps[w];

    for (int kt = 0; kt < T; kt += KTL) {
        __syncthreads();
        {
            const unsigned short* src = khl + (size_t)(kt + skey) * 2048 + kch * 8;
            *(short8*)&Ks_hi[skey * KS_STRIDE + kch * 8] = *(const short8*)src;
            *(short8*)&Ks_lo[skey * KS_STRIDE + kch * 8] = *(const short8*)(src + 64);
            *(short8*)&Vt[vd * VT_STRIDE + vch * 8] =
                *(const short8*)(vtb + (size_t)vd * T + kt + vch * 8);
        }
        __syncthreads();

        // QK^T: 2 key sub-tiles x (2 chunks x 3 split-terms)
        floatx4 a0 = {0,0,0,0}, a1 = {0,0,0,0};
#pragma unroll
        for (int c = 0; c < 2; ++c) {
            const int ko = c * 32 + quad * 8;
            short8 kh0 = *(const short8*)&Ks_hi[n16 * KS_STRIDE + ko];
            short8 kl0 = *(const short8*)&Ks_lo[n16 * KS_STRIDE + ko];
            short8 kh1 = *(const short8*)&Ks_hi[(16 + n16) * KS_STRIDE + ko];
            short8 kl1 = *(const short8*)&Ks_lo[(16 + n16) * KS_STRIDE + ko];
            a0 = mfma_bf16(qh[c], kh0, a0);
            a0 = mfma_bf16(qh[c], kl0, a0);
            a0 = mfma_bf16(ql[c], kh0, a0);
            a1 = mfma_bf16(qh[c], kh1, a1);
            a1 = mfma_bf16(qh[c], kl1, a1);
            a1 = mfma_bf16(ql[c], kh1, a1);
        }

        // online softmax (DPP reductions) + P -> LDS (bf16)
#pragma unroll
        for (int r = 0; r < 4; ++r) {
            float mx = row_max16(fmaxf(a0[r], a1[r]));
            float mn = fmaxf(mrow[r], mx);
            float fac = __expf(mrow[r] - mn);
            mrow[r] = mn;
            float p0 = __expf(a0[r] - mn);
            float p1 = __expf(a1[r] - mn);
            float s = row_sum16(p0 + p1);
            lrow[r] = lrow[r] * fac + s;
            o0[r] *= fac; o1[r] *= fac; o2[r] *= fac; o3[r] *= fac;
            Pw[(quad * 4 + r) * VT_STRIDE + n16]      = bf16_rne(p0);
            Pw[(quad * 4 + r) * VT_STRIDE + 16 + n16] = bf16_rne(p1);
        }

        // PV
        {
            short8 pa = *(const short8*)&Pw[n16 * VT_STRIDE + quad * 8];
            short8 v0 = *(const short8*)&Vt[n16 * VT_STRIDE + quad * 8];
            short8 v1 = *(const short8*)&Vt[(16 + n16) * VT_STRIDE + quad * 8];
            short8 v2 = *(const short8*)&Vt[(32 + n16) * VT_STRIDE + quad * 8];
            short8 v3 = *(const short8*)&Vt[(48 + n16) * VT_STRIDE + quad * 8];
            o0 = mfma_bf16(pa, v0, o0);
            o1 = mfma_bf16(pa, v1, o1);
            o2 = mfma_bf16(pa, v2, o2);
            o3 = mfma_bf16(pa, v3, o3);
        }
    }

#pragma unroll
    for (int r = 0; r < 4; ++r) {
        float inv = 1.0f / lrow[r];
        int row = blockIdx.x * QTILE + w * 16 + quad * 4 + r;
        float* yp = Y + (size_t)(b * T + row) * C + h * 64 + n16;
        yp[0]  = o0[r] * inv;
        yp[16] = o1[r] * inv;
        yp[32] = o2[r] * inv;
        yp[48] = o3[r] * inv;
    }
}

extern "C" void kernel_launch(void* const* d_in, const int* in_sizes, int n_in,
                              void* d_out, int out_size, void* d_ws, size_t ws_size,
                              hipStream_t stream)
{
    const float* x    = (const float*)d_in[0];
    const float* Wq   = (const float*)d_in[1];
    const float* Wk   = (const float*)d_in[2];
    const float* Wv   = (const float*)d_in[3];
    const float* Wo   = (const float*)d_in[4];
    const float* s_qk = (const float*)d_in[5];
    float* out = (float*)d_out;

    constexpr int B = 2, T = 2048, C = 1024, H = 16;
    constexpr int M = B * T;

    // workspace map (64 MB):
    //  [0,16M)   Qb  fp32 (rope in place)
    //  [16,32M)  Khl fp32 from mgemm, then bf16 hi|lo after rope (in place)
    //  [32,40M)  Vbf bf16 [t][C] from mgemm
    //  [40,48M)  vt  bf16 [bh][d][t]
    //  [48,64M)  Yb  fp32 (rope table aliased at its start before attn)
    char* ws = (char*)d_ws;
    float* Qb           = (float*)(ws);
    float* Kf           = (float*)(ws + (size_t)16 * 1024 * 1024);
    unsigned short* Khl = (unsigned short*)Kf;
    unsigned short* Vbf = (unsigned short*)(ws + (size_t)32 * 1024 * 1024);
    unsigned short* vt  = (unsigned short*)(ws + (size_t)40 * 1024 * 1024);
    float* Yb           = (float*)(ws + (size_t)48 * 1024 * 1024);
    float2* tab         = (float2*)Yb;

    dim3 blk(256);

    rope_table<<<dim3(T * 32 / 256), blk, 0, stream>>>(tab);
    mgemm_qkv<<<dim3(M / 128, C / 128, 3), blk, 0, stream>>>(x, Wq, Wk, Wv, Qb, Kf, Vbf);
    rope_norm<<<dim3(2 * B * T * H / 4), blk, 0, stream>>>(Qb, Khl, s_qk, tab);
    vtrans<<<dim3(T / 64, B * H), blk, 0, stream>>>(Vbf, vt);
    attn_mfma<<<dim3(T / QTILE, B * H), blk, 0, stream>>>(Qb, Khl, vt, Yb);
    mgemm_o<<<dim3(M / 128, C / 128), blk, 0, stream>>>(Yb, Wo, out);
}

// Round 9
// 343.744 us; speedup vs baseline: 6.3196x; 1.0879x over previous
//
#include <hip/hip_runtime.h>
#include <math.h>

// nGPT attention. B=2, T=2048, C=1024, H=16, D=64.
// R9 bisection: R6/R8's GEMM path (pre-split bf16 hi/lo inputs, pure-copy
// staging, register prefetch, bf16-A mgemm1, attn->bf16 Y->mgemm_o) is
// numerically identical to R5 and retained. attn reverted to the R5-proven
// body VERBATIM (KTL=32, __expf softmax, DPP max+sum, RNE P rounding, no
// register prefetch) except the epilogue stores Y as bf16.
// R8 failed at absmax 1.234 -- bug is in one of R6's attn deltas (KTL=64 /
// l-via-MFMA / base-2 / cheap-P-round / prefetch); this round isolates it.
// Q/K projections bf16x3 (logit error amplified ~1024x); V/Wo plain bf16.

typedef short short8 __attribute__((ext_vector_type(8)));
typedef float floatx4 __attribute__((ext_vector_type(4)));

__device__ __forceinline__ unsigned short bf16_rne(float x) {
    unsigned u = __float_as_uint(x);
    u += 0x7FFF + ((u >> 16) & 1);
    return (unsigned short)(u >> 16);
}

__device__ __forceinline__ floatx4 mfma_bf16(short8 a, short8 b, floatx4 c) {
    asm("v_mfma_f32_16x16x32_bf16 %0, %1, %2, %0" : "+v"(c) : "v"(a), "v"(b));
    return c;
}

// ---- DPP 16-lane butterfly reductions (VALU pipe) ----
template<int CTRL>
__device__ __forceinline__ float dpp_mov_f(float x) {
    return __int_as_float(__builtin_amdgcn_update_dpp(
        __float_as_int(x), __float_as_int(x), CTRL, 0xF, 0xF, false));
}
__device__ __forceinline__ float row_max16(float x) {
    x = fmaxf(x, dpp_mov_f<0xB1>(x));    // quad_perm(1,0,3,2)
    x = fmaxf(x, dpp_mov_f<0x4E>(x));    // quad_perm(2,3,0,1)
    x = fmaxf(x, dpp_mov_f<0x141>(x));   // row_half_mirror
    x = fmaxf(x, dpp_mov_f<0x140>(x));   // row_mirror
    return x;
}
__device__ __forceinline__ float row_sum16(float x) {
    x += dpp_mov_f<0xB1>(x);
    x += dpp_mov_f<0x4E>(x);
    x += dpp_mov_f<0x141>(x);
    x += dpp_mov_f<0x140>(x);
    return x;
}

// ---------------- fp32 -> bf16 hi/lo split (done once) ----------------
__global__ __launch_bounds__(256) void split_hl(const float* __restrict__ src,
    unsigned short* __restrict__ hi, unsigned short* __restrict__ lo)
{
    size_t i = ((size_t)blockIdx.x * 256 + threadIdx.x) * 8;
    float4 f0 = *(const float4*)(src + i);
    float4 f1 = *(const float4*)(src + i + 4);
    float f[8] = {f0.x, f0.y, f0.z, f0.w, f1.x, f1.y, f1.z, f1.w};
    short8 h, l;
#pragma unroll
    for (int j = 0; j < 8; ++j) {
        unsigned short hb = bf16_rne(f[j]);
        h[j] = (short)hb;
        l[j] = (short)bf16_rne(f[j] - __uint_as_float((unsigned)hb << 16));
    }
    *(short8*)(hi + i) = h;
    *(short8*)(lo + i) = l;
}

// ---------------- MFMA GEMM bodies ----------------
#define LSTR 40   // shorts per LDS row (32 + 8 pad)

// 3-term bf16x3: C = Ah@Bh^T + Ah@Bl^T + Al@Bh^T, all inputs pre-split bf16.
__device__ __forceinline__ void mgemm3_body(unsigned short* lds,
    const unsigned short* __restrict__ Ah, const unsigned short* __restrict__ Al,
    const unsigned short* __restrict__ Bh, const unsigned short* __restrict__ Bl,
    float* __restrict__ Cm, int bm, int bn)
{
    constexpr int Kd = 1024, Nd = 1024;
    unsigned short* LAh = lds;
    unsigned short* LBh = lds + 128 * LSTR;
    unsigned short* LAl = lds + 2 * 128 * LSTR;
    unsigned short* LBl = lds + 3 * 128 * LSTR;

    const int tid = threadIdx.x;
    const int srow = tid >> 1, skc = (tid & 1) << 4;
    const unsigned short* pah = Ah + (size_t)(bm + srow) * Kd + skc;
    const unsigned short* pal = Al + (size_t)(bm + srow) * Kd + skc;
    const unsigned short* pbh = Bh + (size_t)(bn + srow) * Kd + skc;
    const unsigned short* pbl = Bl + (size_t)(bn + srow) * Kd + skc;
    unsigned short* dah = &LAh[srow * LSTR + skc];
    unsigned short* dal = &LAl[srow * LSTR + skc];
    unsigned short* dbh = &LBh[srow * LSTR + skc];
    unsigned short* dbl = &LBl[srow * LSTR + skc];

    const int lane = tid & 63, w = tid >> 6;
    const int n16 = lane & 15, quad = lane >> 4;
    const int m0 = (w & 1) << 6, n0 = (w >> 1) << 6;

    floatx4 acc[4][4];
#pragma unroll
    for (int j = 0; j < 4; ++j)
#pragma unroll
        for (int i = 0; i < 4; ++i) acc[j][i] = (floatx4){0.f, 0.f, 0.f, 0.f};

    short8 rah0 = *(const short8*)(pah),     rah1 = *(const short8*)(pah + 8);
    short8 ral0 = *(const short8*)(pal),     ral1 = *(const short8*)(pal + 8);
    short8 rbh0 = *(const short8*)(pbh),     rbh1 = *(const short8*)(pbh + 8);
    short8 rbl0 = *(const short8*)(pbl),     rbl1 = *(const short8*)(pbl + 8);

    for (int kt = 0; kt < Kd; kt += 32) {
        __syncthreads();
        *(short8*)dah = rah0; *(short8*)(dah + 8) = rah1;
        *(short8*)dal = ral0; *(short8*)(dal + 8) = ral1;
        *(short8*)dbh = rbh0; *(short8*)(dbh + 8) = rbh1;
        *(short8*)dbl = rbl0; *(short8*)(dbl + 8) = rbl1;
        __syncthreads();
        if (kt + 32 < Kd) {
            rah0 = *(const short8*)(pah + kt + 32); rah1 = *(const short8*)(pah + kt + 40);
            ral0 = *(const short8*)(pal + kt + 32); ral1 = *(const short8*)(pal + kt + 40);
            rbh0 = *(const short8*)(pbh + kt + 32); rbh1 = *(const short8*)(pbh + kt + 40);
            rbl0 = *(const short8*)(pbl + kt + 32); rbl1 = *(const short8*)(pbl + kt + 40);
        }
        short8 ah[4], al[4];
#pragma unroll
        for (int i = 0; i < 4; ++i) {
            ah[i] = *(const short8*)&LAh[(m0 + i * 16 + n16) * LSTR + quad * 8];
            al[i] = *(const short8*)&LAl[(m0 + i * 16 + n16) * LSTR + quad * 8];
        }
#pragma unroll
        for (int j = 0; j < 4; ++j) {
            short8 bh = *(const short8*)&LBh[(n0 + j * 16 + n16) * LSTR + quad * 8];
            short8 bl = *(const short8*)&LBl[(n0 + j * 16 + n16) * LSTR + quad * 8];
#pragma unroll
            for (int i = 0; i < 4; ++i) {
                acc[j][i] = mfma_bf16(ah[i], bh, acc[j][i]);
                acc[j][i] = mfma_bf16(ah[i], bl, acc[j][i]);
                acc[j][i] = mfma_bf16(al[i], bh, acc[j][i]);
            }
        }
    }

#pragma unroll
    for (int j = 0; j < 4; ++j)
#pragma unroll
        for (int i = 0; i < 4; ++i) {
            float* cp = Cm + (size_t)(bm + m0 + i * 16 + quad * 4) * Nd
                        + bn + n0 + j * 16 + n16;
#pragma unroll
            for (int r = 0; r < 4; ++r)
                cp[(size_t)r * Nd] = acc[j][i][r];
        }
}

// 1-term bf16: A pre-converted bf16, W fp32 converted in staging.
template<bool OUT16>
__device__ __forceinline__ void mgemm1_body(unsigned short* lds,
    const unsigned short* __restrict__ Abf, const float* __restrict__ Wf,
    void* __restrict__ Out, int bm, int bn)
{
    constexpr int Kd = 1024, Nd = 1024;
    unsigned short* LA = lds;
    unsigned short* LB = lds + 128 * LSTR;

    const int tid = threadIdx.x;
    const int srow = tid >> 1, skc = (tid & 1) << 4;
    const unsigned short* pa = Abf + (size_t)(bm + srow) * Kd + skc;
    const float* pw = Wf + (size_t)(bn + srow) * Kd + skc;
    unsigned short* da = &LA[srow * LSTR + skc];
    unsigned short* db = &LB[srow * LSTR + skc];

    const int lane = tid & 63, w = tid >> 6;
    const int n16 = lane & 15, quad = lane >> 4;
    const int m0 = (w & 1) << 6, n0 = (w >> 1) << 6;

    floatx4 acc[4][4];
#pragma unroll
    for (int j = 0; j < 4; ++j)
#pragma unroll
        for (int i = 0; i < 4; ++i) acc[j][i] = (floatx4){0.f, 0.f, 0.f, 0.f};

    short8 ra0 = *(const short8*)(pa), ra1 = *(const short8*)(pa + 8);
    float4 w0 = *(const float4*)(pw),      w1 = *(const float4*)(pw + 4);
    float4 w2 = *(const float4*)(pw + 8),  w3 = *(const float4*)(pw + 12);

    for (int kt = 0; kt < Kd; kt += 32) {
        float fw[16];
        *(float4*)&fw[0] = w0; *(float4*)&fw[4] = w1;
        *(float4*)&fw[8] = w2; *(float4*)&fw[12] = w3;
        short8 h0, h1;
#pragma unroll
        for (int j = 0; j < 8; ++j) {
            h0[j] = (short)bf16_rne(fw[j]);
            h1[j] = (short)bf16_rne(fw[8 + j]);
        }
        __syncthreads();
        *(short8*)da = ra0; *(short8*)(da + 8) = ra1;
        *(short8*)db = h0;  *(short8*)(db + 8) = h1;
        __syncthreads();
        if (kt + 32 < Kd) {
            ra0 = *(const short8*)(pa + kt + 32); ra1 = *(const short8*)(pa + kt + 40);
            w0 = *(const float4*)(pw + kt + 32);  w1 = *(const float4*)(pw + kt + 36);
            w2 = *(const float4*)(pw + kt + 40);  w3 = *(const float4*)(pw + kt + 44);
        }
        short8 ah[4];
#pragma unroll
        for (int i = 0; i < 4; ++i)
            ah[i] = *(const short8*)&LA[(m0 + i * 16 + n16) * LSTR + quad * 8];
#pragma unroll
        for (int j = 0; j < 4; ++j) {
            short8 bh = *(const short8*)&LB[(n0 + j * 16 + n16) * LSTR + quad * 8];
#pragma unroll
            for (int i = 0; i < 4; ++i)
                acc[j][i] = mfma_bf16(ah[i], bh, acc[j][i]);
        }
    }

#pragma unroll
    for (int j = 0; j < 4; ++j)
#pragma unroll
        for (int i = 0; i < 4; ++i) {
            size_t base = (size_t)(bm + m0 + i * 16 + quad * 4) * Nd
                          + bn + n0 + j * 16 + n16;
            if (OUT16) {
                unsigned short* cp = (unsigned short*)Out + base;
#pragma unroll
                for (int r = 0; r < 4; ++r)
                    cp[(size_t)r * Nd] = bf16_rne(acc[j][i][r]);
            } else {
                float* cp = (float*)Out + base;
#pragma unroll
                for (int r = 0; r < 4; ++r)
                    cp[(size_t)r * Nd] = acc[j][i][r];
            }
        }
}

__global__ __launch_bounds__(256) void mgemm_qkv(
    const unsigned short* __restrict__ xh, const unsigned short* __restrict__ xl,
    const unsigned short* __restrict__ Wqh, const unsigned short* __restrict__ Wql,
    const unsigned short* __restrict__ Wkh, const unsigned short* __restrict__ Wkl,
    const float* __restrict__ Wv,
    float* __restrict__ Qb, float* __restrict__ Kf, unsigned short* __restrict__ Vbf)
{
    __shared__ __align__(16) unsigned short lds[4 * 128 * LSTR];   // 40 KB
    const int bm = blockIdx.x * 128, bn = blockIdx.y * 128;
    if (blockIdx.z == 2)      mgemm1_body<true>(lds, xh, Wv, Vbf, bm, bn);
    else if (blockIdx.z == 0) mgemm3_body(lds, xh, xl, Wqh, Wql, Qb, bm, bn);
    else                      mgemm3_body(lds, xh, xl, Wkh, Wkl, Kf, bm, bn);
}

__global__ __launch_bounds__(256) void mgemm_o(const unsigned short* __restrict__ Ybf,
    const float* __restrict__ Wo, float* __restrict__ Out)
{
    __shared__ __align__(16) unsigned short lds[2 * 128 * LSTR];   // 20 KB
    mgemm1_body<false>(lds, Ybf, Wo, Out, blockIdx.x * 128, blockIdx.y * 128);
}

// ---------------- RoPE ----------------
__global__ __launch_bounds__(256) void rope_table(float2* __restrict__ tab)
{
    int idx = blockIdx.x * 256 + threadIdx.x;   // t*32 + p
    int t = idx >> 5, p = idx & 31;
    double invf = pow(10000.0, -(double)p / 32.0);
    double sd, cd;
    sincos((double)t * invf, &sd, &cd);
    tab[idx] = make_float2((float)cd, (float)sd);
}

// One wave per (b,t,h,{q|k}); lane = d. RoPE + L2-normalize + scale.
// Q: in-place fp32 (sqrt(D)=8 folded). K: bf16 hi|lo over its own fp32 row.
__global__ __launch_bounds__(256) void rope_norm(float* __restrict__ Q,
                                                 unsigned short* __restrict__ Khl,
                                                 const float* __restrict__ s_qk,
                                                 const float2* __restrict__ tab)
{
    constexpr int T = 2048, H = 16;
    int wid = blockIdx.x * 4 + (threadIdx.x >> 6);
    const int lane = threadIdx.x & 63;
    const int sel = wid & 1; wid >>= 1;
    const int h = wid & (H - 1); wid >>= 4;
    const int t = wid & (T - 1); wid >>= 11;
    const int b = wid;

    const size_t idx = ((size_t)(b * T + t)) * H + h;
    float v = sel ? ((const float*)Khl)[idx * 64 + lane] : Q[idx * 64 + lane];

    float2 cs2 = tab[(t << 5) + (lane >> 1)];
    const float cs = cs2.x, sn = cs2.y;

    float partner = __shfl_xor(v, 1, 64);
    float rot = (lane & 1) ? partner : -partner;
    float r = v * cs + rot * sn;

    float ssq = r * r;
#pragma unroll
    for (int off = 32; off; off >>= 1) ssq += __shfl_xor(ssq, off, 64);
    float nrm = fmaxf(sqrtf(ssq), 1e-12f);

    float scale = s_qk[h * 64 + lane] * 32.0f;   // s_qk * sqrt(C)
    if (!sel) {
        Q[idx * 64 + lane] = r / nrm * (scale * 8.0f);   // fold sqrt(D) into Q
    } else {
        float val = r / nrm * scale;
        unsigned short hi = bf16_rne(val);
        unsigned short lo = bf16_rne(val - __uint_as_float((unsigned)hi << 16));
        unsigned short* row = Khl + idx * 128;
        row[lane] = hi;
        row[64 + lane] = lo;
    }
}

// ---------------- V transpose: Vbf[t][h*64+d] -> vt[bh][d][t] (bf16) --------
__global__ __launch_bounds__(256) void vtrans(const unsigned short* __restrict__ Vbf,
                                              unsigned short* __restrict__ vt)
{
    constexpr int T = 2048, C = 1024;
    __shared__ unsigned short tile[64 * 72];
    const int bh = blockIdx.y;
    const int h = bh & 15, b = bh >> 4;
    const int t0 = blockIdx.x * 64;

    const int tl = threadIdx.x & 63;
    const int dc = threadIdx.x >> 6;
    const unsigned short* src = Vbf + (size_t)(b * T + t0 + tl) * C + h * 64 + dc * 16;
    short8 s0 = *(const short8*)src;
    short8 s1 = *(const short8*)(src + 8);
#pragma unroll
    for (int j = 0; j < 8; ++j) tile[(dc * 16 + j) * 72 + tl] = (unsigned short)s0[j];
#pragma unroll
    for (int j = 0; j < 8; ++j) tile[(dc * 16 + 8 + j) * 72 + tl] = (unsigned short)s1[j];
    __syncthreads();

    const int d = threadIdx.x >> 2;
    const int tc = threadIdx.x & 3;
    short8 r0 = *(const short8*)&tile[d * 72 + tc * 16];
    short8 r1 = *(const short8*)&tile[d * 72 + tc * 16 + 8];
    unsigned short* dst = vt + ((size_t)bh * 64 + d) * T + t0 + tc * 16;
    *(short8*)dst = r0;
    *(short8*)(dst + 8) = r1;
}

// ---------------- MFMA flash attention (R5-proven body; bf16 Y store) -------
#define QTILE 64
#define KTL 32
#define KS_STRIDE 72
#define VT_STRIDE 40

__global__ __launch_bounds__(256) void attn_mfma(const float* __restrict__ Q,
    const unsigned short* __restrict__ Khl, const unsigned short* __restrict__ vt,
    unsigned short* __restrict__ Ybf)
{
    constexpr int T = 2048, C = 1024;
    __shared__ __align__(16) unsigned short Ks_hi[KTL * KS_STRIDE];
    __shared__ __align__(16) unsigned short Ks_lo[KTL * KS_STRIDE];
    __shared__ __align__(16) unsigned short Vt[64 * VT_STRIDE];
    __shared__ __align__(16) unsigned short Ps[4][16 * VT_STRIDE];

    const int bh = blockIdx.y;
    const int h = bh & 15;
    const int b = bh >> 4;
    const int w = threadIdx.x >> 6;
    const int lane = threadIdx.x & 63;
    const int n16 = lane & 15;
    const int quad = lane >> 4;

    // Q A-fragments (hi/lo), loaded once and split.
    const int qrow = blockIdx.x * QTILE + w * 16 + n16;
    short8 qh[2], ql[2];
#pragma unroll
    for (int c = 0; c < 2; ++c) {
        const float* p = Q + ((size_t)(b * T + qrow)) * C + h * 64 + c * 32 + quad * 8;
        float4 f0 = *(const float4*)p;
        float4 f1 = *(const float4*)(p + 4);
        float f[8] = {f0.x, f0.y, f0.z, f0.w, f1.x, f1.y, f1.z, f1.w};
#pragma unroll
        for (int j = 0; j < 8; ++j) {
            unsigned short hb = bf16_rne(f[j]);
            float hf = __uint_as_float((unsigned)hb << 16);
            qh[c][j] = (short)hb;
            ql[c][j] = (short)bf16_rne(f[j] - hf);
        }
    }

    floatx4 o0 = {0,0,0,0}, o1 = {0,0,0,0}, o2 = {0,0,0,0}, o3 = {0,0,0,0};
    float mrow[4] = {-1e30f, -1e30f, -1e30f, -1e30f};
    float lrow[4] = {0.f, 0.f, 0.f, 0.f};

    // staging maps
    const unsigned short* khl = Khl + (((size_t)b * T) * 16 + h) * 128;
    const unsigned short* vtb = vt + (size_t)bh * 64 * T;
    const int skey = threadIdx.x >> 3;      // 0..31
    const int kch  = threadIdx.x & 7;       // 8-short chunk
    const int vd   = threadIdx.x >> 2;      // 0..63
    const int vch  = threadIdx.x & 3;       // 8-key chunk
    unsigned short* Pw = Ps[w];

    for (int kt = 0; kt < T; kt += KTL) {
        __syncthreads();
        {
            const unsigned short* src = khl + (size_t)(kt + skey) * 2048 + kch * 8;
            *(short8*)&Ks_hi[skey * KS_STRIDE + kch * 8] = *(const short8*)src;
            *(short8*)&Ks_lo[skey * KS_STRIDE + kch * 8] = *(const short8*)(src + 64);
            *(short8*)&Vt[vd * VT_STRIDE + vch * 8] =
                *(const short8*)(vtb + (size_t)vd * T + kt + vch * 8);
        }
        __syncthreads();

        // QK^T: 2 key sub-tiles x (2 chunks x 3 split-terms)
        floatx4 a0 = {0,0,0,0}, a1 = {0,0,0,0};
#pragma unroll
        for (int c = 0; c < 2; ++c) {
            const int ko = c * 32 + quad * 8;
            short8 kh0 = *(const short8*)&Ks_hi[n16 * KS_STRIDE + ko];
            short8 kl0 = *(const short8*)&Ks_lo[n16 * KS_STRIDE + ko];
            short8 kh1 = *(const short8*)&Ks_hi[(16 + n16) * KS_STRIDE + ko];
            short8 kl1 = *(const short8*)&Ks_lo[(16 + n16) * KS_STRIDE + ko];
            a0 = mfma_bf16(qh[c], kh0, a0);
            a0 = mfma_bf16(qh[c], kl0, a0);
            a0 = mfma_bf16(ql[c], kh0, a0);
            a1 = mfma_bf16(qh[c], kh1, a1);
            a1 = mfma_bf16(qh[c], kl1, a1);
            a1 = mfma_bf16(ql[c], kh1, a1);
        }

        // online softmax (DPP reductions) + P -> LDS (bf16)
#pragma unroll
        for (int r = 0; r < 4; ++r) {
            float mx = row_max16(fmaxf(a0[r], a1[r]));
            float mn = fmaxf(mrow[r], mx);
            float fac = __expf(mrow[r] - mn);
            mrow[r] = mn;
            float p0 = __expf(a0[r] - mn);
            float p1 = __expf(a1[r] - mn);
            float s = row_sum16(p0 + p1);
            lrow[r] = lrow[r] * fac + s;
            o0[r] *= fac; o1[r] *= fac; o2[r] *= fac; o3[r] *= fac;
            Pw[(quad * 4 + r) * VT_STRIDE + n16]      = bf16_rne(p0);
            Pw[(quad * 4 + r) * VT_STRIDE + 16 + n16] = bf16_rne(p1);
        }

        // PV
        {
            short8 pa = *(const short8*)&Pw[n16 * VT_STRIDE + quad * 8];
            short8 v0 = *(const short8*)&Vt[n16 * VT_STRIDE + quad * 8];
            short8 v1 = *(const short8*)&Vt[(16 + n16) * VT_STRIDE + quad * 8];
            short8 v2 = *(const short8*)&Vt[(32 + n16) * VT_STRIDE + quad * 8];
            short8 v3 = *(const short8*)&Vt[(48 + n16) * VT_STRIDE + quad * 8];
            o0 = mfma_bf16(pa, v0, o0);
            o1 = mfma_bf16(pa, v1, o1);
            o2 = mfma_bf16(pa, v2, o2);
            o3 = mfma_bf16(pa, v3, o3);
        }
    }

    // epilogue: normalize, write Y as bf16
#pragma unroll
    for (int r = 0; r < 4; ++r) {
        float inv = 1.0f / lrow[r];
        int row = blockIdx.x * QTILE + w * 16 + quad * 4 + r;
        unsigned short* yp = Ybf + (size_t)(b * T + row) * C + h * 64 + n16;
        yp[0]  = bf16_rne(o0[r] * inv);
        yp[16] = bf16_rne(o1[r] * inv);
        yp[32] = bf16_rne(o2[r] * inv);
        yp[48] = bf16_rne(o3[r] * inv);
    }
}

extern "C" void kernel_launch(void* const* d_in, const int* in_sizes, int n_in,
                              void* d_out, int out_size, void* d_ws, size_t ws_size,
                              hipStream_t stream)
{
    const float* x    = (const float*)d_in[0];
    const float* Wq   = (const float*)d_in[1];
    const float* Wk   = (const float*)d_in[2];
    const float* Wv   = (const float*)d_in[3];
    const float* Wo   = (const float*)d_in[4];
    const float* s_qk = (const float*)d_in[5];
    float* out = (float*)d_out;

    constexpr int B = 2, T = 2048, C = 1024, H = 16;
    constexpr int M = B * T;

    // workspace map (64 MB, phase-aliased):
    //  [0,16M)   Qb fp32 (rope in place)
    //  [16,32M)  Kf fp32 -> Khl bf16 hi|lo (rope, in place)
    //  [32,40M)  Vbf bf16 [t][C]
    //  [40,48M)  xh (dies after mgemm_qkv) -> tab (rope) -> vt [bh][d][t]
    //  [48,56M)  xl (dies after mgemm_qkv) -> Ybf bf16
    //  [56,64M)  Wqh,Wql,Wkh,Wkl (die after mgemm_qkv)
    char* ws = (char*)d_ws;
    float* Qb           = (float*)ws;
    float* Kf           = (float*)(ws + ((size_t)16 << 20));
    unsigned short* Khl = (unsigned short*)Kf;
    unsigned short* Vbf = (unsigned short*)(ws + ((size_t)32 << 20));
    unsigned short* xh  = (unsigned short*)(ws + ((size_t)40 << 20));
    unsigned short* xl  = (unsigned short*)(ws + ((size_t)48 << 20));
    unsigned short* vt  = xh;                     // after mgemm_qkv
    unsigned short* Ybf = xl;                     // after mgemm_qkv
    float2* tab         = (float2*)xh;            // between mgemm_qkv and vtrans
    unsigned short* Wqh = (unsigned short*)(ws + ((size_t)56 << 20));
    unsigned short* Wql = Wqh + (1u << 20);
    unsigned short* Wkh = Wql + (1u << 20);
    unsigned short* Wkl = Wkh + (1u << 20);

    dim3 blk(256);

    split_hl<<<dim3(M * C / (256 * 8)), blk, 0, stream>>>(x, xh, xl);
    split_hl<<<dim3(C * C / (256 * 8)), blk, 0, stream>>>(Wq, Wqh, Wql);
    split_hl<<<dim3(C * C / (256 * 8)), blk, 0, stream>>>(Wk, Wkh, Wkl);

    mgemm_qkv<<<dim3(M / 128, C / 128, 3), blk, 0, stream>>>(
        xh, xl, Wqh, Wql, Wkh, Wkl, Wv, Qb, Kf, Vbf);

    rope_table<<<dim3(T * 32 / 256), blk, 0, stream>>>(tab);
    rope_norm<<<dim3(2 * B * T * H / 4), blk, 0, stream>>>(Qb, Khl, s_qk, tab);
    vtrans<<<dim3(T / 64, B * H), blk, 0, stream>>>(Vbf, vt);

    attn_mfma<<<dim3(T / QTILE, B * H), blk, 0, stream>>>(Qb, Khl, vt, Ybf);

    mgemm_o<<<dim3(M / 128, C / 128), blk, 0, stream>>>(Ybf, Wo, out);
}

// Round 10
// 330.421 us; speedup vs baseline: 6.5744x; 1.0403x over previous
//
#include <hip/hip_runtime.h>
#include <math.h>

// nGPT attention. B=2, T=2048, C=1024, H=16, D=64.
// R10 = R9 + attn KTL 32->64 ONLY (single-variable bisection of the R8 bug).
// Numerics held identical to R9: __expf softmax, DPP max+sum, RNE P rounding,
// scalar lrow, load-after-barrier staging (no register prefetch, no l-via-MFMA,
// no base-2 fold). GEMM path: pre-split bf16 hi/lo inputs, pure-copy staging,
// register prefetch, attn->bf16 Y->mgemm_o (proven in R9).
// Q/K projections bf16x3 (logit error amplified ~1024x); V/Wo plain bf16.

typedef short short8 __attribute__((ext_vector_type(8)));
typedef float floatx4 __attribute__((ext_vector_type(4)));

__device__ __forceinline__ unsigned short bf16_rne(float x) {
    unsigned u = __float_as_uint(x);
    u += 0x7FFF + ((u >> 16) & 1);
    return (unsigned short)(u >> 16);
}

__device__ __forceinline__ floatx4 mfma_bf16(short8 a, short8 b, floatx4 c) {
    asm("v_mfma_f32_16x16x32_bf16 %0, %1, %2, %0" : "+v"(c) : "v"(a), "v"(b));
    return c;
}

// ---- DPP 16-lane butterfly reductions (VALU pipe) ----
template<int CTRL>
__device__ __forceinline__ float dpp_mov_f(float x) {
    return __int_as_float(__builtin_amdgcn_update_dpp(
        __float_as_int(x), __float_as_int(x), CTRL, 0xF, 0xF, false));
}
__device__ __forceinline__ float row_max16(float x) {
    x = fmaxf(x, dpp_mov_f<0xB1>(x));    // quad_perm(1,0,3,2)
    x = fmaxf(x, dpp_mov_f<0x4E>(x));    // quad_perm(2,3,0,1)
    x = fmaxf(x, dpp_mov_f<0x141>(x));   // row_half_mirror
    x = fmaxf(x, dpp_mov_f<0x140>(x));   // row_mirror
    return x;
}
__device__ __forceinline__ float row_sum16(float x) {
    x += dpp_mov_f<0xB1>(x);
    x += dpp_mov_f<0x4E>(x);
    x += dpp_mov_f<0x141>(x);
    x += dpp_mov_f<0x140>(x);
    return x;
}

// ---------------- fp32 -> bf16 hi/lo split (done once) ----------------
__global__ __launch_bounds__(256) void split_hl(const float* __restrict__ src,
    unsigned short* __restrict__ hi, unsigned short* __restrict__ lo)
{
    size_t i = ((size_t)blockIdx.x * 256 + threadIdx.x) * 8;
    float4 f0 = *(const float4*)(src + i);
    float4 f1 = *(const float4*)(src + i + 4);
    float f[8] = {f0.x, f0.y, f0.z, f0.w, f1.x, f1.y, f1.z, f1.w};
    short8 h, l;
#pragma unroll
    for (int j = 0; j < 8; ++j) {
        unsigned short hb = bf16_rne(f[j]);
        h[j] = (short)hb;
        l[j] = (short)bf16_rne(f[j] - __uint_as_float((unsigned)hb << 16));
    }
    *(short8*)(hi + i) = h;
    *(short8*)(lo + i) = l;
}

// ---------------- MFMA GEMM bodies ----------------
#define LSTR 40   // shorts per LDS row (32 + 8 pad)

// 3-term bf16x3: C = Ah@Bh^T + Ah@Bl^T + Al@Bh^T, all inputs pre-split bf16.
__device__ __forceinline__ void mgemm3_body(unsigned short* lds,
    const unsigned short* __restrict__ Ah, const unsigned short* __restrict__ Al,
    const unsigned short* __restrict__ Bh, const unsigned short* __restrict__ Bl,
    float* __restrict__ Cm, int bm, int bn)
{
    constexpr int Kd = 1024, Nd = 1024;
    unsigned short* LAh = lds;
    unsigned short* LBh = lds + 128 * LSTR;
    unsigned short* LAl = lds + 2 * 128 * LSTR;
    unsigned short* LBl = lds + 3 * 128 * LSTR;

    const int tid = threadIdx.x;
    const int srow = tid >> 1, skc = (tid & 1) << 4;
    const unsigned short* pah = Ah + (size_t)(bm + srow) * Kd + skc;
    const unsigned short* pal = Al + (size_t)(bm + srow) * Kd + skc;
    const unsigned short* pbh = Bh + (size_t)(bn + srow) * Kd + skc;
    const unsigned short* pbl = Bl + (size_t)(bn + srow) * Kd + skc;
    unsigned short* dah = &LAh[srow * LSTR + skc];
    unsigned short* dal = &LAl[srow * LSTR + skc];
    unsigned short* dbh = &LBh[srow * LSTR + skc];
    unsigned short* dbl = &LBl[srow * LSTR + skc];

    const int lane = tid & 63, w = tid >> 6;
    const int n16 = lane & 15, quad = lane >> 4;
    const int m0 = (w & 1) << 6, n0 = (w >> 1) << 6;

    floatx4 acc[4][4];
#pragma unroll
    for (int j = 0; j < 4; ++j)
#pragma unroll
        for (int i = 0; i < 4; ++i) acc[j][i] = (floatx4){0.f, 0.f, 0.f, 0.f};

    short8 rah0 = *(const short8*)(pah),     rah1 = *(const short8*)(pah + 8);
    short8 ral0 = *(const short8*)(pal),     ral1 = *(const short8*)(pal + 8);
    short8 rbh0 = *(const short8*)(pbh),     rbh1 = *(const short8*)(pbh + 8);
    short8 rbl0 = *(const short8*)(pbl),     rbl1 = *(const short8*)(pbl + 8);

    for (int kt = 0; kt < Kd; kt += 32) {
        __syncthreads();
        *(short8*)dah = rah0; *(short8*)(dah + 8) = rah1;
        *(short8*)dal = ral0; *(short8*)(dal + 8) = ral1;
        *(short8*)dbh = rbh0; *(short8*)(dbh + 8) = rbh1;
        *(short8*)dbl = rbl0; *(short8*)(dbl + 8) = rbl1;
        __syncthreads();
        if (kt + 32 < Kd) {
            rah0 = *(const short8*)(pah + kt + 32); rah1 = *(const short8*)(pah + kt + 40);
            ral0 = *(const short8*)(pal + kt + 32); ral1 = *(const short8*)(pal + kt + 40);
            rbh0 = *(const short8*)(pbh + kt + 32); rbh1 = *(const short8*)(pbh + kt + 40);
            rbl0 = *(const short8*)(pbl + kt + 32); rbl1 = *(const short8*)(pbl + kt + 40);
        }
        short8 ah[4], al[4];
#pragma unroll
        for (int i = 0; i < 4; ++i) {
            ah[i] = *(const short8*)&LAh[(m0 + i * 16 + n16) * LSTR + quad * 8];
            al[i] = *(const short8*)&LAl[(m0 + i * 16 + n16) * LSTR + quad * 8];
        }
#pragma unroll
        for (int j = 0; j < 4; ++j) {
            short8 bh = *(const short8*)&LBh[(n0 + j * 16 + n16) * LSTR + quad * 8];
            short8 bl = *(const short8*)&LBl[(n0 + j * 16 + n16) * LSTR + quad * 8];
#pragma unroll
            for (int i = 0; i < 4; ++i) {
                acc[j][i] = mfma_bf16(ah[i], bh, acc[j][i]);
                acc[j][i] = mfma_bf16(ah[i], bl, acc[j][i]);
                acc[j][i] = mfma_bf16(al[i], bh, acc[j][i]);
            }
        }
    }

#pragma unroll
    for (int j = 0; j < 4; ++j)
#pragma unroll
        for (int i = 0; i < 4; ++i) {
            float* cp = Cm + (size_t)(bm + m0 + i * 16 + quad * 4) * Nd
                        + bn + n0 + j * 16 + n16;
#pragma unroll
            for (int r = 0; r < 4; ++r)
                cp[(size_t)r * Nd] = acc[j][i][r];
        }
}

// 1-term bf16: A pre-converted bf16, W fp32 converted in staging.
template<bool OUT16>
__device__ __forceinline__ void mgemm1_body(unsigned short* lds,
    const unsigned short* __restrict__ Abf, const float* __restrict__ Wf,
    void* __restrict__ Out, int bm, int bn)
{
    constexpr int Kd = 1024, Nd = 1024;
    unsigned short* LA = lds;
    unsigned short* LB = lds + 128 * LSTR;

    const int tid = threadIdx.x;
    const int srow = tid >> 1, skc = (tid & 1) << 4;
    const unsigned short* pa = Abf + (size_t)(bm + srow) * Kd + skc;
    const float* pw = Wf + (size_t)(bn + srow) * Kd + skc;
    unsigned short* da = &LA[srow * LSTR + skc];
    unsigned short* db = &LB[srow * LSTR + skc];

    const int lane = tid & 63, w = tid >> 6;
    const int n16 = lane & 15, quad = lane >> 4;
    const int m0 = (w & 1) << 6, n0 = (w >> 1) << 6;

    floatx4 acc[4][4];
#pragma unroll
    for (int j = 0; j < 4; ++j)
#pragma unroll
        for (int i = 0; i < 4; ++i) acc[j][i] = (floatx4){0.f, 0.f, 0.f, 0.f};

    short8 ra0 = *(const short8*)(pa), ra1 = *(const short8*)(pa + 8);
    float4 w0 = *(const float4*)(pw),      w1 = *(const float4*)(pw + 4);
    float4 w2 = *(const float4*)(pw + 8),  w3 = *(const float4*)(pw + 12);

    for (int kt = 0; kt < Kd; kt += 32) {
        float fw[16];
        *(float4*)&fw[0] = w0; *(float4*)&fw[4] = w1;
        *(float4*)&fw[8] = w2; *(float4*)&fw[12] = w3;
        short8 h0, h1;
#pragma unroll
        for (int j = 0; j < 8; ++j) {
            h0[j] = (short)bf16_rne(fw[j]);
            h1[j] = (short)bf16_rne(fw[8 + j]);
        }
        __syncthreads();
        *(short8*)da = ra0; *(short8*)(da + 8) = ra1;
        *(short8*)db = h0;  *(short8*)(db + 8) = h1;
        __syncthreads();
        if (kt + 32 < Kd) {
            ra0 = *(const short8*)(pa + kt + 32); ra1 = *(const short8*)(pa + kt + 40);
            w0 = *(const float4*)(pw + kt + 32);  w1 = *(const float4*)(pw + kt + 36);
            w2 = *(const float4*)(pw + kt + 40);  w3 = *(const float4*)(pw + kt + 44);
        }
        short8 ah[4];
#pragma unroll
        for (int i = 0; i < 4; ++i)
            ah[i] = *(const short8*)&LA[(m0 + i * 16 + n16) * LSTR + quad * 8];
#pragma unroll
        for (int j = 0; j < 4; ++j) {
            short8 bh = *(const short8*)&LB[(n0 + j * 16 + n16) * LSTR + quad * 8];
#pragma unroll
            for (int i = 0; i < 4; ++i)
                acc[j][i] = mfma_bf16(ah[i], bh, acc[j][i]);
        }
    }

#pragma unroll
    for (int j = 0; j < 4; ++j)
#pragma unroll
        for (int i = 0; i < 4; ++i) {
            size_t base = (size_t)(bm + m0 + i * 16 + quad * 4) * Nd
                          + bn + n0 + j * 16 + n16;
            if (OUT16) {
                unsigned short* cp = (unsigned short*)Out + base;
#pragma unroll
                for (int r = 0; r < 4; ++r)
                    cp[(size_t)r * Nd] = bf16_rne(acc[j][i][r]);
            } else {
                float* cp = (float*)Out + base;
#pragma unroll
                for (int r = 0; r < 4; ++r)
                    cp[(size_t)r * Nd] = acc[j][i][r];
            }
        }
}

__global__ __launch_bounds__(256) void mgemm_qkv(
    const unsigned short* __restrict__ xh, const unsigned short* __restrict__ xl,
    const unsigned short* __restrict__ Wqh, const unsigned short* __restrict__ Wql,
    const unsigned short* __restrict__ Wkh, const unsigned short* __restrict__ Wkl,
    const float* __restrict__ Wv,
    float* __restrict__ Qb, float* __restrict__ Kf, unsigned short* __restrict__ Vbf)
{
    __shared__ __align__(16) unsigned short lds[4 * 128 * LSTR];   // 40 KB
    const int bm = blockIdx.x * 128, bn = blockIdx.y * 128;
    if (blockIdx.z == 2)      mgemm1_body<true>(lds, xh, Wv, Vbf, bm, bn);
    else if (blockIdx.z == 0) mgemm3_body(lds, xh, xl, Wqh, Wql, Qb, bm, bn);
    else                      mgemm3_body(lds, xh, xl, Wkh, Wkl, Kf, bm, bn);
}

__global__ __launch_bounds__(256) void mgemm_o(const unsigned short* __restrict__ Ybf,
    const float* __restrict__ Wo, float* __restrict__ Out)
{
    __shared__ __align__(16) unsigned short lds[2 * 128 * LSTR];   // 20 KB
    mgemm1_body<false>(lds, Ybf, Wo, Out, blockIdx.x * 128, blockIdx.y * 128);
}

// ---------------- RoPE ----------------
__global__ __launch_bounds__(256) void rope_table(float2* __restrict__ tab)
{
    int idx = blockIdx.x * 256 + threadIdx.x;   // t*32 + p
    int t = idx >> 5, p = idx & 31;
    double invf = pow(10000.0, -(double)p / 32.0);
    double sd, cd;
    sincos((double)t * invf, &sd, &cd);
    tab[idx] = make_float2((float)cd, (float)sd);
}

// One wave per (b,t,h,{q|k}); lane = d. RoPE + L2-normalize + scale.
// Q: in-place fp32 (sqrt(D)=8 folded). K: bf16 hi|lo over its own fp32 row.
__global__ __launch_bounds__(256) void rope_norm(float* __restrict__ Q,
                                                 unsigned short* __restrict__ Khl,
                                                 const float* __restrict__ s_qk,
                                                 const float2* __restrict__ tab)
{
    constexpr int T = 2048, H = 16;
    int wid = blockIdx.x * 4 + (threadIdx.x >> 6);
    const int lane = threadIdx.x & 63;
    const int sel = wid & 1; wid >>= 1;
    const int h = wid & (H - 1); wid >>= 4;
    const int t = wid & (T - 1); wid >>= 11;
    const int b = wid;

    const size_t idx = ((size_t)(b * T + t)) * H + h;
    float v = sel ? ((const float*)Khl)[idx * 64 + lane] : Q[idx * 64 + lane];

    float2 cs2 = tab[(t << 5) + (lane >> 1)];
    const float cs = cs2.x, sn = cs2.y;

    float partner = __shfl_xor(v, 1, 64);
    float rot = (lane & 1) ? partner : -partner;
    float r = v * cs + rot * sn;

    float ssq = r * r;
#pragma unroll
    for (int off = 32; off; off >>= 1) ssq += __shfl_xor(ssq, off, 64);
    float nrm = fmaxf(sqrtf(ssq), 1e-12f);

    float scale = s_qk[h * 64 + lane] * 32.0f;   // s_qk * sqrt(C)
    if (!sel) {
        Q[idx * 64 + lane] = r / nrm * (scale * 8.0f);   // fold sqrt(D) into Q
    } else {
        float val = r / nrm * scale;
        unsigned short hi = bf16_rne(val);
        unsigned short lo = bf16_rne(val - __uint_as_float((unsigned)hi << 16));
        unsigned short* row = Khl + idx * 128;
        row[lane] = hi;
        row[64 + lane] = lo;
    }
}

// ---------------- V transpose: Vbf[t][h*64+d] -> vt[bh][d][t] (bf16) --------
__global__ __launch_bounds__(256) void vtrans(const unsigned short* __restrict__ Vbf,
                                              unsigned short* __restrict__ vt)
{
    constexpr int T = 2048, C = 1024;
    __shared__ unsigned short tile[64 * 72];
    const int bh = blockIdx.y;
    const int h = bh & 15, b = bh >> 4;
    const int t0 = blockIdx.x * 64;

    const int tl = threadIdx.x & 63;
    const int dc = threadIdx.x >> 6;
    const unsigned short* src = Vbf + (size_t)(b * T + t0 + tl) * C + h * 64 + dc * 16;
    short8 s0 = *(const short8*)src;
    short8 s1 = *(const short8*)(src + 8);
#pragma unroll
    for (int j = 0; j < 8; ++j) tile[(dc * 16 + j) * 72 + tl] = (unsigned short)s0[j];
#pragma unroll
    for (int j = 0; j < 8; ++j) tile[(dc * 16 + 8 + j) * 72 + tl] = (unsigned short)s1[j];
    __syncthreads();

    const int d = threadIdx.x >> 2;
    const int tc = threadIdx.x & 3;
    short8 r0 = *(const short8*)&tile[d * 72 + tc * 16];
    short8 r1 = *(const short8*)&tile[d * 72 + tc * 16 + 8];
    unsigned short* dst = vt + ((size_t)bh * 64 + d) * T + t0 + tc * 16;
    *(short8*)dst = r0;
    *(short8*)(dst + 8) = r1;
}

// ---------------- MFMA flash attention ----------------
// KTL=64 keys/tile (R10 single delta vs R9); R5/R9 numerics preserved:
// __expf softmax, DPP max+sum, RNE P rounding, scalar lrow, staging loads
// after the barrier (no register prefetch).
#define QTILE 64
#define KTL 64
#define KSTR 72

__global__ __launch_bounds__(256) void attn_mfma(const float* __restrict__ Q,
    const unsigned short* __restrict__ Khl, const unsigned short* __restrict__ vt,
    unsigned short* __restrict__ Ybf)
{
    constexpr int T = 2048, C = 1024;
    __shared__ __align__(16) unsigned short Ks_hi[KTL * KSTR];
    __shared__ __align__(16) unsigned short Ks_lo[KTL * KSTR];
    __shared__ __align__(16) unsigned short Vt[64 * KSTR];
    __shared__ __align__(16) unsigned short Ps[4][16 * KSTR];

    const int bh = blockIdx.y;
    const int h = bh & 15;
    const int b = bh >> 4;
    const int w = threadIdx.x >> 6;
    const int lane = threadIdx.x & 63;
    const int n16 = lane & 15;
    const int quad = lane >> 4;

    // Q A-fragments (hi/lo), loaded once and split.
    const int qrow = blockIdx.x * QTILE + w * 16 + n16;
    short8 qh[2], ql[2];
#pragma unroll
    for (int c = 0; c < 2; ++c) {
        const float* p = Q + ((size_t)(b * T + qrow)) * C + h * 64 + c * 32 + quad * 8;
        float4 f0 = *(const float4*)p;
        float4 f1 = *(const float4*)(p + 4);
        float f[8] = {f0.x, f0.y, f0.z, f0.w, f1.x, f1.y, f1.z, f1.w};
#pragma unroll
        for (int j = 0; j < 8; ++j) {
            unsigned short hb = bf16_rne(f[j]);
            float hf = __uint_as_float((unsigned)hb << 16);
            qh[c][j] = (short)hb;
            ql[c][j] = (short)bf16_rne(f[j] - hf);
        }
    }

    floatx4 o0 = {0,0,0,0}, o1 = {0,0,0,0}, o2 = {0,0,0,0}, o3 = {0,0,0,0};
    float mrow[4] = {-1e30f, -1e30f, -1e30f, -1e30f};
    float lrow[4] = {0.f, 0.f, 0.f, 0.f};

    // staging maps: 64 K rows (hi+lo) and 64 V dims, 16-short chunks
    const unsigned short* khl = Khl + (((size_t)b * T) * 16 + h) * 128;
    const unsigned short* vtb = vt + (size_t)bh * 64 * T;
    const int sr = threadIdx.x >> 2;        // 0..63 (k-row / v-dim)
    const int sc = (threadIdx.x & 3) * 16;  // 0,16,32,48
    unsigned short* Pw = Ps[w];

    for (int kt = 0; kt < T; kt += KTL) {
        __syncthreads();
        {
            const unsigned short* src = khl + (size_t)(kt + sr) * 2048 + sc;
            *(short8*)&Ks_hi[sr * KSTR + sc]     = *(const short8*)src;
            *(short8*)&Ks_hi[sr * KSTR + sc + 8] = *(const short8*)(src + 8);
            *(short8*)&Ks_lo[sr * KSTR + sc]     = *(const short8*)(src + 64);
            *(short8*)&Ks_lo[sr * KSTR + sc + 8] = *(const short8*)(src + 72);
            const unsigned short* vsrc = vtb + (size_t)sr * T + kt + sc;
            *(short8*)&Vt[sr * KSTR + sc]     = *(const short8*)vsrc;
            *(short8*)&Vt[sr * KSTR + sc + 8] = *(const short8*)(vsrc + 8);
        }
        __syncthreads();

        // QK^T: 4 key groups x (2 chunks x 3 split-terms)
        floatx4 s0 = {0,0,0,0}, s1 = {0,0,0,0}, s2 = {0,0,0,0}, s3 = {0,0,0,0};
#pragma unroll
        for (int c = 0; c < 2; ++c) {
            const int ko = c * 32 + quad * 8;
            short8 kh, kl;
            kh = *(const short8*)&Ks_hi[n16 * KSTR + ko];
            kl = *(const short8*)&Ks_lo[n16 * KSTR + ko];
            s0 = mfma_bf16(qh[c], kh, s0); s0 = mfma_bf16(qh[c], kl, s0); s0 = mfma_bf16(ql[c], kh, s0);
            kh = *(const short8*)&Ks_hi[(16 + n16) * KSTR + ko];
            kl = *(const short8*)&Ks_lo[(16 + n16) * KSTR + ko];
            s1 = mfma_bf16(qh[c], kh, s1); s1 = mfma_bf16(qh[c], kl, s1); s1 = mfma_bf16(ql[c], kh, s1);
            kh = *(const short8*)&Ks_hi[(32 + n16) * KSTR + ko];
            kl = *(const short8*)&Ks_lo[(32 + n16) * KSTR + ko];
            s2 = mfma_bf16(qh[c], kh, s2); s2 = mfma_bf16(qh[c], kl, s2); s2 = mfma_bf16(ql[c], kh, s2);
            kh = *(const short8*)&Ks_hi[(48 + n16) * KSTR + ko];
            kl = *(const short8*)&Ks_lo[(48 + n16) * KSTR + ko];
            s3 = mfma_bf16(qh[c], kh, s3); s3 = mfma_bf16(qh[c], kl, s3); s3 = mfma_bf16(ql[c], kh, s3);
        }

        // online softmax (R9 numerics: __expf, DPP max+sum, RNE P)
#pragma unroll
        for (int r = 0; r < 4; ++r) {
            float mx = fmaxf(fmaxf(s0[r], s1[r]), fmaxf(s2[r], s3[r]));
            mx = row_max16(mx);
            float mn = fmaxf(mrow[r], mx);
            float fac = __expf(mrow[r] - mn);
            mrow[r] = mn;
            float p0 = __expf(s0[r] - mn);
            float p1 = __expf(s1[r] - mn);
            float p2 = __expf(s2[r] - mn);
            float p3 = __expf(s3[r] - mn);
            float s = row_sum16(((p0 + p1) + (p2 + p3)));
            lrow[r] = lrow[r] * fac + s;
            o0[r] *= fac; o1[r] *= fac; o2[r] *= fac; o3[r] *= fac;
            const int pr = (quad * 4 + r) * KSTR;
            Pw[pr + n16]      = bf16_rne(p0);
            Pw[pr + 16 + n16] = bf16_rne(p1);
            Pw[pr + 32 + n16] = bf16_rne(p2);
            Pw[pr + 48 + n16] = bf16_rne(p3);
        }

        // PV: keys 0..31 via pa0, 32..63 via pa1
        {
            short8 pa0 = *(const short8*)&Pw[n16 * KSTR + quad * 8];
            short8 pa1 = *(const short8*)&Pw[n16 * KSTR + 32 + quad * 8];
            short8 v0, v1;
            v0 = *(const short8*)&Vt[n16 * KSTR + quad * 8];
            v1 = *(const short8*)&Vt[n16 * KSTR + 32 + quad * 8];
            o0 = mfma_bf16(pa0, v0, o0); o0 = mfma_bf16(pa1, v1, o0);
            v0 = *(const short8*)&Vt[(16 + n16) * KSTR + quad * 8];
            v1 = *(const short8*)&Vt[(16 + n16) * KSTR + 32 + quad * 8];
            o1 = mfma_bf16(pa0, v0, o1); o1 = mfma_bf16(pa1, v1, o1);
            v0 = *(const short8*)&Vt[(32 + n16) * KSTR + quad * 8];
            v1 = *(const short8*)&Vt[(32 + n16) * KSTR + 32 + quad * 8];
            o2 = mfma_bf16(pa0, v0, o2); o2 = mfma_bf16(pa1, v1, o2);
            v0 = *(const short8*)&Vt[(48 + n16) * KSTR + quad * 8];
            v1 = *(const short8*)&Vt[(48 + n16) * KSTR + 32 + quad * 8];
            o3 = mfma_bf16(pa0, v0, o3); o3 = mfma_bf16(pa1, v1, o3);
        }
    }

    // epilogue: normalize, write Y as bf16
#pragma unroll
    for (int r = 0; r < 4; ++r) {
        float inv = 1.0f / lrow[r];
        int row = blockIdx.x * QTILE + w * 16 + quad * 4 + r;
        unsigned short* yp = Ybf + (size_t)(b * T + row) * C + h * 64 + n16;
        yp[0]  = bf16_rne(o0[r] * inv);
        yp[16] = bf16_rne(o1[r] * inv);
        yp[32] = bf16_rne(o2[r] * inv);
        yp[48] = bf16_rne(o3[r] * inv);
    }
}

extern "C" void kernel_launch(void* const* d_in, const int* in_sizes, int n_in,
                              void* d_out, int out_size, void* d_ws, size_t ws_size,
                              hipStream_t stream)
{
    const float* x    = (const float*)d_in[0];
    const float* Wq   = (const float*)d_in[1];
    const float* Wk   = (const float*)d_in[2];
    const float* Wv   = (const float*)d_in[3];
    const float* Wo   = (const float*)d_in[4];
    const float* s_qk = (const float*)d_in[5];
    float* out = (float*)d_out;

    constexpr int B = 2, T = 2048, C = 1024, H = 16;
    constexpr int M = B * T;

    // workspace map (64 MB, phase-aliased):
    //  [0,16M)   Qb fp32 (rope in place)
    //  [16,32M)  Kf fp32 -> Khl bf16 hi|lo (rope, in place)
    //  [32,40M)  Vbf bf16 [t][C]
    //  [40,48M)  xh (dies after mgemm_qkv) -> tab (rope) -> vt [bh][d][t]
    //  [48,56M)  xl (dies after mgemm_qkv) -> Ybf bf16
    //  [56,64M)  Wqh,Wql,Wkh,Wkl (die after mgemm_qkv)
    char* ws = (char*)d_ws;
    float* Qb           = (float*)ws;
    float* Kf           = (float*)(ws + ((size_t)16 << 20));
    unsigned short* Khl = (unsigned short*)Kf;
    unsigned short* Vbf = (unsigned short*)(ws + ((size_t)32 << 20));
    unsigned short* xh  = (unsigned short*)(ws + ((size_t)40 << 20));
    unsigned short* xl  = (unsigned short*)(ws + ((size_t)48 << 20));
    unsigned short* vt  = xh;                     // after mgemm_qkv
    unsigned short* Ybf = xl;                     // after mgemm_qkv
    float2* tab         = (float2*)xh;            // between mgemm_qkv and vtrans
    unsigned short* Wqh = (unsigned short*)(ws + ((size_t)56 << 20));
    unsigned short* Wql = Wqh + (1u << 20);
    unsigned short* Wkh = Wql + (1u << 20);
    unsigned short* Wkl = Wkh + (1u << 20);

    dim3 blk(256);

    split_hl<<<dim3(M * C / (256 * 8)), blk, 0, stream>>>(x, xh, xl);
    split_hl<<<dim3(C * C / (256 * 8)), blk, 0, stream>>>(Wq, Wqh, Wql);
    split_hl<<<dim3(C * C / (256 * 8)), blk, 0, stream>>>(Wk, Wkh, Wkl);

    mgemm_qkv<<<dim3(M / 128, C / 128, 3), blk, 0, stream>>>(
        xh, xl, Wqh, Wql, Wkh, Wkl, Wv, Qb, Kf, Vbf);

    rope_table<<<dim3(T * 32 / 256), blk, 0, stream>>>(tab);
    rope_norm<<<dim3(2 * B * T * H / 4), blk, 0, stream>>>(Qb, Khl, s_qk, tab);
    vtrans<<<dim3(T / 64, B * H), blk, 0, stream>>>(Vbf, vt);

    attn_mfma<<<dim3(T / QTILE, B * H), blk, 0, stream>>>(Qb, Khl, vt, Ybf);

    mgemm_o<<<dim3(M / 128, C / 128), blk, 0, stream>>>(Ybf, Wo, out);
}